// Round 13
// baseline (154.367 us; speedup 1.0000x reference)
//
#include <hip/hip_runtime.h>
#include <hip/hip_bf16.h>

// B=2, S=2048, D=1024, H=16, Hd=64
// cvt(fused) -> QKV GEMM + fused LN/split/V-frag-major epilogue ->
// flash attention (swapped-QK, kv-split 2x, T15 double-pipeline:
// QK(cur) || softmax+PV(prev)) -> proj GEMM

typedef __attribute__((ext_vector_type(8)))  short bf16x8;   // 8 bf16 (4 VGPRs)
typedef __attribute__((ext_vector_type(4)))  float f32x4;
typedef __attribute__((ext_vector_type(16))) float f32x16;

__device__ __forceinline__ unsigned short f2bf(float f) {
  union { float f; unsigned u; } v; v.f = f;
  unsigned r = v.u + 0x7FFFu + ((v.u >> 16) & 1u);
  return (unsigned short)(r >> 16);
}

__device__ __forceinline__ unsigned pkbf(float a, float b) {
  unsigned r;
  asm("v_cvt_pk_bf16_f32 %0, %1, %2" : "=v"(r) : "v"(a), "v"(b));
  return r;
}

__device__ __forceinline__ void pl32swap(unsigned& x, unsigned& y) {
  asm("v_permlane32_swap_b32 %0, %1" : "+v"(x), "+v"(y));
}

// raw-rate exp2 (args bounded by defer-max; denormal flush-to-0 fine here)
__device__ __forceinline__ float fexp2(float x) {
  float r; asm("v_exp_f32 %0, %1" : "=v"(r) : "v"(x)); return r;
}

__device__ __forceinline__ void gld_lds16(const void* g, void* l) {
  __builtin_amdgcn_global_load_lds(
      (const __attribute__((address_space(1))) void*)g,
      (__attribute__((address_space(3))) void*)l, 16, 0, 0);
}

// ---------------- fused fp32 -> bf16 convert ----------------
__global__ __launch_bounds__(256) void k_cvt3(const float* __restrict__ x,
                                              const float* __restrict__ wq,
                                              const float* __restrict__ wp,
                                              unsigned short* __restrict__ d) {
  int i = blockIdx.x * 256 + threadIdx.x;       // 0 .. 2097151 float4 units
  const float* s;
  int off;
  if (i < 1048576)      { s = x;  off = i; }
  else if (i < 1835008) { s = wq; off = i - 1048576; }
  else                  { s = wp; off = i - 1835008; }
  float4 v = ((const float4*)s)[off];
  ushort4 o;
  o.x = f2bf(v.x); o.y = f2bf(v.y); o.z = f2bf(v.z); o.w = f2bf(v.w);
  ((ushort4*)d)[i] = o;
}

// ---------------- generic NT bf16 GEMM (proj) ----------------
template<int BM, int BN, int WM, int WN>
__global__ __launch_bounds__(256) void k_gemm(
    const unsigned short* __restrict__ A, const unsigned short* __restrict__ B,
    const float* __restrict__ bias, float* __restrict__ C, int M, int N, int K)
{
  constexpr int FM = BM / WM / 16;
  constexpr int FN = BN / WN / 16;
  __shared__ unsigned short lA[BM * 64];
  __shared__ unsigned short lB[BN * 64];
  int tid = threadIdx.x;
  int lane = tid & 63, wid = tid >> 6;
  int lg = lane >> 4, lo = lane & 15;
  int wm = wid / WN, wn = wid % WN;
  int m0 = blockIdx.y * BM, n0 = blockIdx.x * BN;

  f32x4 acc[FM][FN];
#pragma unroll
  for (int i = 0; i < FM; ++i)
#pragma unroll
    for (int j = 0; j < FN; ++j) acc[i][j] = (f32x4){0.f, 0.f, 0.f, 0.f};

  const int srow = tid >> 3, scol = (tid & 7) * 8;

  for (int kt = 0; kt < K; kt += 64) {
    __syncthreads();
#pragma unroll
    for (int i = 0; i < BM / 32; ++i)
      gld_lds16(A + (size_t)(m0 + srow + 32 * i) * K + kt + scol,
                &lA[(srow + 32 * i) * 64 + scol]);
#pragma unroll
    for (int i = 0; i < BN / 32; ++i)
      gld_lds16(B + (size_t)(n0 + srow + 32 * i) * K + kt + scol,
                &lB[(srow + 32 * i) * 64 + scol]);
    __syncthreads();

#pragma unroll
    for (int ks = 0; ks < 2; ++ks) {
      bf16x8 af[FM], bfr[FN];
#pragma unroll
      for (int i = 0; i < FM; ++i)
        af[i] = *(const bf16x8*)&lA[(wm * (BM / WM) + i * 16 + lo) * 64 + ks * 32 + lg * 8];
#pragma unroll
      for (int j = 0; j < FN; ++j)
        bfr[j] = *(const bf16x8*)&lB[(wn * (BN / WN) + j * 16 + lo) * 64 + ks * 32 + lg * 8];
      __builtin_amdgcn_s_setprio(1);
#pragma unroll
      for (int i = 0; i < FM; ++i)
#pragma unroll
        for (int j = 0; j < FN; ++j)
          acc[i][j] = __builtin_amdgcn_mfma_f32_16x16x32_bf16(af[i], bfr[j], acc[i][j], 0, 0, 0);
      __builtin_amdgcn_s_setprio(0);
    }
  }

#pragma unroll
  for (int j = 0; j < FN; ++j) {
    int col = n0 + wn * (BN / WN) + j * 16 + lo;
    float bb = bias[col];
#pragma unroll
    for (int i = 0; i < FM; ++i)
#pragma unroll
      for (int r = 0; r < 4; ++r) {
        int row = m0 + wm * (BM / WM) + i * 16 + lg * 4 + r;
        C[(size_t)row * N + col] = acc[i][j][r] + bb;
      }
  }
}

// ---------------- QKV GEMM with fused LN + split + V frag-major (unchanged) ----------------
__global__ __launch_bounds__(256) void k_gemm_qkv(
    const unsigned short* __restrict__ A,   // x_bf [4096][1024]
    const unsigned short* __restrict__ B,   // wq_bf [3072][1024]
    const float* __restrict__ bias,         // [3072]
    const float* __restrict__ qg, const float* __restrict__ qb,
    const float* __restrict__ kg, const float* __restrict__ kb,
    unsigned short* __restrict__ qh,        // [32][2048][64]
    unsigned short* __restrict__ kh,        // [32][2048][64]
    unsigned short* __restrict__ vf)        // [32][131072] frag-major
{
  __shared__ unsigned short lA[128 * 64];
  __shared__ unsigned short lB[128 * 64];
  int tid = threadIdx.x;
  int lane = tid & 63, wid = tid >> 6;
  int lg = lane >> 4, lo = lane & 15;
  int wm = wid >> 1, wn = wid & 1;
  int m0 = blockIdx.y * 128, n0 = blockIdx.x * 128;
  const int K = 1024;

  f32x4 acc[4][4];
#pragma unroll
  for (int i = 0; i < 4; ++i)
#pragma unroll
    for (int j = 0; j < 4; ++j) acc[i][j] = (f32x4){0.f, 0.f, 0.f, 0.f};

  const int srow = tid >> 3, scol = (tid & 7) * 8;

  for (int kt = 0; kt < K; kt += 64) {
    __syncthreads();
#pragma unroll
    for (int i = 0; i < 4; ++i)
      gld_lds16(A + (size_t)(m0 + srow + 32 * i) * K + kt + scol,
                &lA[(srow + 32 * i) * 64 + scol]);
#pragma unroll
    for (int i = 0; i < 4; ++i)
      gld_lds16(B + (size_t)(n0 + srow + 32 * i) * K + kt + scol,
                &lB[(srow + 32 * i) * 64 + scol]);
    __syncthreads();

#pragma unroll
    for (int ks = 0; ks < 2; ++ks) {
      bf16x8 af[4], bfr[4];
#pragma unroll
      for (int i = 0; i < 4; ++i)
        af[i] = *(const bf16x8*)&lA[(wm * 64 + i * 16 + lo) * 64 + ks * 32 + lg * 8];
#pragma unroll
      for (int j = 0; j < 4; ++j)
        bfr[j] = *(const bf16x8*)&lB[(wn * 64 + j * 16 + lo) * 64 + ks * 32 + lg * 8];
      __builtin_amdgcn_s_setprio(1);
#pragma unroll
      for (int i = 0; i < 4; ++i)
#pragma unroll
        for (int j = 0; j < 4; ++j)
          acc[i][j] = __builtin_amdgcn_mfma_f32_16x16x32_bf16(af[i], bfr[j], acc[i][j], 0, 0, 0);
      __builtin_amdgcn_s_setprio(0);
    }
  }

  // ---- fused epilogue ----
  int m0b = m0 & 2047;
  int bb_ = m0 >> 11;
  int hcol = (n0 + wn * 64) >> 6;      // 0..15 q, 16..31 k, 32..47 v
  float bias4[4];
#pragma unroll
  for (int j = 0; j < 4; ++j) bias4[j] = bias[n0 + wn * 64 + j * 16 + lo];

  if (hcol >= 32) {
    int bh = bb_ * 16 + (hcol - 32);
    int T = m0b >> 7;
    int hi_ = lg >> 1;
    int j8b = (lg & 1) * 4;
    unsigned short* vbase = vf + (size_t)bh * 131072 + T * 8192 + hi_ * 256 + j8b;
#pragma unroll
    for (int i = 0; i < 4; ++i) {
      int ss = wm * 4 + i;
#pragma unroll
      for (int j = 0; j < 4; ++j) {
        int dh = j >> 1, dp = (j & 1) * 16 + lo;
        uint2 w;
        w.x = pkbf(acc[i][j][0] + bias4[j], acc[i][j][1] + bias4[j]);
        w.y = pkbf(acc[i][j][2] + bias4[j], acc[i][j][3] + bias4[j]);
        *(uint2*)(vbase + ss * 1024 + dh * 512 + dp * 8) = w;
      }
    }
  } else {
    bool isq = hcol < 16;
    int bh = bb_ * 16 + (isq ? hcol : hcol - 16);
    const float* g = isq ? qg : kg;
    const float* bt = isq ? qb : kb;
    float osc = isq ? 0.18033688f : 1.0f;   // 0.125 * log2(e) folded into q
    float g4[4], t4[4];
#pragma unroll
    for (int j = 0; j < 4; ++j) {
      g4[j] = g[j * 16 + lo] * osc;
      t4[j] = bt[j * 16 + lo] * osc;
    }
    unsigned short* dst = (isq ? qh : kh) + (size_t)bh * 131072;
#pragma unroll
    for (int i = 0; i < 4; ++i) {
#pragma unroll
      for (int r = 0; r < 4; ++r) {
        float v0 = acc[i][0][r] + bias4[0];
        float v1 = acc[i][1][r] + bias4[1];
        float v2 = acc[i][2][r] + bias4[2];
        float v3 = acc[i][3][r] + bias4[3];
        float sm = (v0 + v1) + (v2 + v3);
        sm += __shfl_xor(sm, 1, 64); sm += __shfl_xor(sm, 2, 64);
        sm += __shfl_xor(sm, 4, 64); sm += __shfl_xor(sm, 8, 64);
        float mu = sm * (1.0f / 64.0f);
        float d0 = v0 - mu, d1 = v1 - mu, d2 = v2 - mu, d3 = v3 - mu;
        float vv = (d0 * d0 + d1 * d1) + (d2 * d2 + d3 * d3);
        vv += __shfl_xor(vv, 1, 64); vv += __shfl_xor(vv, 2, 64);
        vv += __shfl_xor(vv, 4, 64); vv += __shfl_xor(vv, 8, 64);
        float rs = rsqrtf(vv * (1.0f / 64.0f) + 1e-5f);
        int s = m0b + wm * 64 + i * 16 + lg * 4 + r;
        unsigned short* row = dst + (size_t)s * 64 + lo;
        row[0]  = f2bf(fmaf(d0 * rs, g4[0], t4[0]));
        row[16] = f2bf(fmaf(d1 * rs, g4[1], t4[1]));
        row[32] = f2bf(fmaf(d2 * rs, g4[2], t4[2]));
        row[48] = f2bf(fmaf(d3 * rs, g4[3], t4[3]));
      }
    }
  }
}

// ==================== attention v11 helpers ====================

// stage one 16KB tile-pair into LDS buffer (XOR-swizzled global source)
__device__ __forceinline__ void stage_pair(const char* kbytes, int pair,
                                           char* dst, int tid) {
#pragma unroll
  for (int ii = 0; ii < 4; ++ii) {
    int b = ii * 4096 + tid * 16;
    int sb = b ^ (((b >> 7) & 7) << 4);      // involution (bits 4-6)
    gld_lds16(kbytes + (size_t)pair * 16384 + sb, dst + b);
  }
}

// QK^T for this wave's 64-kv tile out of an LDS buffer -> sc (zero-frag init)
__device__ __forceinline__ void qk_body(f32x16 (&sc)[2], const char* lKbuf,
                                        int g, int l31, int hi,
                                        const bf16x8 (&qf)[4], const f32x16& z16) {
  const char* bK = lKbuf + g * 8192;
  __builtin_amdgcn_s_setprio(1);
#pragma unroll
  for (int c = 0; c < 2; ++c) {
    int row = c * 32 + l31;
    int rx = (row * 128) ^ ((row & 7) << 4);
    bf16x8 kf = *(const bf16x8*)(bK + (rx ^ (hi * 16)));
    sc[c] = __builtin_amdgcn_mfma_f32_32x32x16_bf16(kf, qf[0], z16, 0, 0, 0);
#pragma unroll
    for (int s = 1; s < 4; ++s) {
      kf = *(const bf16x8*)(bK + (rx ^ ((2 * s + hi) * 16)));
      sc[c] = __builtin_amdgcn_mfma_f32_32x32x16_bf16(kf, qf[s], sc[c], 0, 0, 0);
    }
  }
  __builtin_amdgcn_s_setprio(0);
}

// softmax + PV for a previously-computed score set (V loaded in-loop from L2)
__device__ __forceinline__ void smpv_body(f32x16 (&sc)[2],
                                          const unsigned short* vt,
                                          float& m, float& lsum,
                                          f32x16& o0, f32x16& o1) {
  // max tree (max3-fusable)
  float r[8];
#pragma unroll
  for (int i2 = 0; i2 < 8; ++i2)
    r[i2] = fmaxf(fmaxf(sc[0][i2], sc[0][i2 + 8]),
                  fmaxf(sc[1][i2], sc[1][i2 + 8]));
  float pm = fmaxf(fmaxf(fmaxf(r[0], r[1]), fmaxf(r[2], r[3])),
                   fmaxf(fmaxf(r[4], r[5]), fmaxf(r[6], r[7])));
  pm = fmaxf(pm, __shfl_xor(pm, 32, 64));

  if (!__all(pm - m <= 8.0f)) {              // defer-max
    float mn = fmaxf(m, pm);
    float fac = fexp2(m - mn);
    m = mn;
    lsum *= fac;
#pragma unroll
    for (int i2 = 0; i2 < 16; ++i2) { o0[i2] *= fac; o1[i2] *= fac; }
  }

  // raw-rate exp2 + tree sum
#pragma unroll
  for (int c = 0; c < 2; ++c)
#pragma unroll
    for (int i2 = 0; i2 < 16; ++i2) sc[c][i2] = fexp2(sc[c][i2] - m);
  float ts[16];
#pragma unroll
  for (int i2 = 0; i2 < 16; ++i2) ts[i2] = sc[0][i2] + sc[1][i2];
#pragma unroll
  for (int d = 8; d; d >>= 1)
#pragma unroll
    for (int i2 = 0; i2 < d; ++i2) ts[i2] += ts[i2 + d];
  lsum += ts[0] + __shfl_xor(ts[0], 32, 64);

  // PV: 4 s-steps of 16 kv; V loaded in-loop (r9 placement, proven)
#pragma unroll
  for (int s = 0; s < 4; ++s) {
    const f32x16& sf = sc[s >> 1];
    const int rb = (s & 1) * 8;
    unsigned d0 = pkbf(sf[rb + 0], sf[rb + 1]);
    unsigned d1 = pkbf(sf[rb + 2], sf[rb + 3]);
    unsigned d2 = pkbf(sf[rb + 4], sf[rb + 5]);
    unsigned d3 = pkbf(sf[rb + 6], sf[rb + 7]);
    pl32swap(d0, d2);
    pl32swap(d1, d3);
    union { unsigned u[4]; bf16x8 v; } pu;
    pu.u[0] = d0; pu.u[1] = d1; pu.u[2] = d2; pu.u[3] = d3;
    bf16x8 v0 = *(const bf16x8*)(vt + s * 1024);
    bf16x8 v1 = *(const bf16x8*)(vt + s * 1024 + 512);
    __builtin_amdgcn_s_setprio(1);
    o0 = __builtin_amdgcn_mfma_f32_32x32x16_bf16(v0, pu.v, o0, 0, 0, 0);
    o1 = __builtin_amdgcn_mfma_f32_32x32x16_bf16(v1, pu.v, o1, 0, 0, 0);
    __builtin_amdgcn_s_setprio(0);
  }
}

// ---------------- flash attention v11: T15 double-pipeline ----------------
// Per iteration: QK(tile i) -> one score set while softmax+PV(tile i-1) runs
// from the other. Two named score sets, explicit 2x-unrolled role swap.
__global__ __launch_bounds__(256, 3) void k_attn(
    const unsigned short* __restrict__ Q,   // [BH][S][64] (pre-scaled)
    const unsigned short* __restrict__ K,   // [BH][S][64]
    const unsigned short* __restrict__ VF,  // [BH][131072] frag-major
    unsigned short* __restrict__ O)         // [B*S][1024] bf16
{
  __shared__ char lK[2][16384];   // 32 KB: [buf][g*8192 + row*128 + col]

  int tid = threadIdx.x;
  int wid = tid >> 6, lane = tid & 63;
  int l31 = lane & 31, hi = lane >> 5;
  int qc = wid >> 1, g = wid & 1;

  int id = blockIdx.x;                       // 1024 blocks, XCD-bijective
  int nid = (id & 7) * 128 + (id >> 3);
  int bh = nid >> 5;
  int q0 = (nid & 31) << 6;                  // 64 q-rows per block
  int q = q0 + qc * 32 + l31;

  const unsigned short* qp = Q + ((size_t)bh * 2048 + q) * 64 + hi * 8;
  bf16x8 qf[4];
#pragma unroll
  for (int s = 0; s < 4; ++s) qf[s] = *(const bf16x8*)(qp + 16 * s);

  const char* kbytes = (const char*)(K + (size_t)bh * 131072);
  const unsigned short* vfb = VF + (size_t)bh * 131072 + lane * 8;

  f32x16 z16;
#pragma unroll
  for (int i = 0; i < 16; ++i) z16[i] = 0.f;
  float m = -1e30f, lsum = 0.0f;
  f32x16 o0 = z16, o1 = z16;

  f32x16 scA[2], scB[2];

  // prologue: stage pair 0, then pair 1; QK(T_g) -> A
  stage_pair(kbytes, 0, lK[0], tid);
  __syncthreads();
  stage_pair(kbytes, 1, lK[1], tid);
  qk_body(scA, lK[0], g, l31, hi, qf, z16);
  __syncthreads();

  // steady state: 7 double-iterations cover iters 1..14
#pragma unroll 1
  for (int ii = 0; ii < 7; ++ii) {
    // iter 2ii+1: QK from buf1 -> B; SMPV(A) = tile 4ii+g
    stage_pair(kbytes, 2 * ii + 2, lK[0], tid);
    qk_body(scB, lK[1], g, l31, hi, qf, z16);
    smpv_body(scA, vfb + (size_t)(4 * ii + g) * 4096, m, lsum, o0, o1);
    __syncthreads();
    // iter 2ii+2: QK from buf0 -> A; SMPV(B) = tile 4ii+2+g
    stage_pair(kbytes, 2 * ii + 3, lK[1], tid);
    qk_body(scA, lK[0], g, l31, hi, qf, z16);
    smpv_body(scB, vfb + (size_t)(4 * ii + 2 + g) * 4096, m, lsum, o0, o1);
    __syncthreads();
  }

  // iter 15: QK(T_15) from buf1 -> B; SMPV(A) = tile 28+g
  qk_body(scB, lK[1], g, l31, hi, qf, z16);
  smpv_body(scA, vfb + (size_t)(28 + g) * 4096, m, lsum, o0, o1);
  // tail: SMPV(B) = tile 30+g
  smpv_body(scB, vfb + (size_t)(30 + g) * 4096, m, lsum, o0, o1);

  // ---- kv-group merge via LDS (lK[0] safe: last read was iter 14, barriered) ----
  float* mb = (float*)&lK[0][0];
  int base = (qc * 64 + lane) * 34;
  if (g) {
#pragma unroll
    for (int i2 = 0; i2 < 16; ++i2) { mb[base + i2] = o0[i2]; mb[base + 16 + i2] = o1[i2]; }
    mb[base + 32] = m; mb[base + 33] = lsum;
  }
  __syncthreads();
  if (!g) {
    float m1 = mb[base + 32], l1 = mb[base + 33];
    float mn = fmaxf(m, m1);
    float f0 = fexp2(m - mn), f1 = fexp2(m1 - mn);
    float linv = 1.0f / (lsum * f0 + l1 * f1);
    float a0 = f0 * linv, a1 = f1 * linv;
    int b = bh >> 4, h = bh & 15;
    unsigned short* ob = O + ((size_t)(b * 2048 + q)) * 1024 + h * 64;
#pragma unroll
    for (int gg = 0; gg < 4; ++gg) {
      uint2 w;
      w.x = pkbf(o0[4 * gg + 0] * a0 + mb[base + 4 * gg + 0] * a1,
                 o0[4 * gg + 1] * a0 + mb[base + 4 * gg + 1] * a1);
      w.y = pkbf(o0[4 * gg + 2] * a0 + mb[base + 4 * gg + 2] * a1,
                 o0[4 * gg + 3] * a0 + mb[base + 4 * gg + 3] * a1);
      *(uint2*)(ob + 8 * gg + 4 * hi) = w;
      w.x = pkbf(o1[4 * gg + 0] * a0 + mb[base + 16 + 4 * gg + 0] * a1,
                 o1[4 * gg + 1] * a0 + mb[base + 16 + 4 * gg + 1] * a1);
      w.y = pkbf(o1[4 * gg + 2] * a0 + mb[base + 16 + 4 * gg + 2] * a1,
                 o1[4 * gg + 3] * a0 + mb[base + 16 + 4 * gg + 3] * a1);
      *(uint2*)(ob + 32 + 8 * gg + 4 * hi) = w;
    }
  }
}

extern "C" void kernel_launch(void* const* d_in, const int* in_sizes, int n_in,
                              void* d_out, int out_size, void* d_ws, size_t ws_size,
                              hipStream_t stream)
{
  (void)in_sizes; (void)n_in; (void)out_size; (void)ws_size;
  const float* x      = (const float*)d_in[0];
  const float* w_qkv  = (const float*)d_in[1];
  const float* b_qkv  = (const float*)d_in[2];
  const float* w_proj = (const float*)d_in[3];
  const float* b_proj = (const float*)d_in[4];
  const float* q_g    = (const float*)d_in[5];
  const float* q_b    = (const float*)d_in[6];
  const float* k_g    = (const float*)d_in[7];
  const float* k_b    = (const float*)d_in[8];
  float* out = (float*)d_out;

  char* p = (char*)d_ws;
  unsigned short* x_bf  = (unsigned short*)p;  p += (size_t)4096 * 1024 * 2;
  unsigned short* wq_bf = (unsigned short*)p;  p += (size_t)3072 * 1024 * 2;
  unsigned short* wp_bf = (unsigned short*)p;  p += (size_t)1024 * 1024 * 2;
  unsigned short* qh    = (unsigned short*)p;  p += (size_t)32 * 2048 * 64 * 2;
  unsigned short* kh    = (unsigned short*)p;  p += (size_t)32 * 2048 * 64 * 2;
  unsigned short* vfr   = (unsigned short*)p;  p += (size_t)32 * 131072 * 2;
  unsigned short* ao    = (unsigned short*)p;  p += (size_t)4096 * 1024 * 2;

  k_cvt3<<<8192, 256, 0, stream>>>(x, w_qkv, w_proj, x_bf);

  k_gemm_qkv<<<dim3(24, 32), 256, 0, stream>>>(x_bf, wq_bf, b_qkv,
                                               q_g, q_b, k_g, k_b, qh, kh, vfr);
  k_attn<<<1024, 256, 0, stream>>>(qh, kh, vfr, ao);
  k_gemm<64, 128, 1, 4><<<dim3(8, 64), 256, 0, stream>>>(ao, wp_bf, b_proj, out, 4096, 1024, 1024);
}

// Round 14
// 154.264 us; speedup vs baseline: 1.0007x; 1.0007x over previous
//
#include <hip/hip_runtime.h>
#include <hip/hip_bf16.h>

// B=2, S=2048, D=1024, H=16, Hd=64
// cvt(fused) -> QKV GEMM + fused LN/split/V-frag-major epilogue ->
// flash attention (swapped-QK, kv-split 2x, T15 double-pipeline:
// QK(cur) || softmax+PV(prev)) -> proj GEMM

typedef __attribute__((ext_vector_type(8)))  short bf16x8;   // 8 bf16 (4 VGPRs)
typedef __attribute__((ext_vector_type(4)))  float f32x4;
typedef __attribute__((ext_vector_type(16))) float f32x16;

__device__ __forceinline__ unsigned short f2bf(float f) {
  union { float f; unsigned u; } v; v.f = f;
  unsigned r = v.u + 0x7FFFu + ((v.u >> 16) & 1u);
  return (unsigned short)(r >> 16);
}

__device__ __forceinline__ unsigned pkbf(float a, float b) {
  unsigned r;
  asm("v_cvt_pk_bf16_f32 %0, %1, %2" : "=v"(r) : "v"(a), "v"(b));
  return r;
}

__device__ __forceinline__ void pl32swap(unsigned& x, unsigned& y) {
  asm("v_permlane32_swap_b32 %0, %1" : "+v"(x), "+v"(y));
}

// raw-rate exp2 (args bounded by defer-max; denormal flush-to-0 fine here)
__device__ __forceinline__ float fexp2(float x) {
  float r; asm("v_exp_f32 %0, %1" : "=v"(r) : "v"(x)); return r;
}

__device__ __forceinline__ void gld_lds16(const void* g, void* l) {
  __builtin_amdgcn_global_load_lds(
      (const __attribute__((address_space(1))) void*)g,
      (__attribute__((address_space(3))) void*)l, 16, 0, 0);
}

// ---------------- fused fp32 -> bf16 convert ----------------
__global__ __launch_bounds__(256) void k_cvt3(const float* __restrict__ x,
                                              const float* __restrict__ wq,
                                              const float* __restrict__ wp,
                                              unsigned short* __restrict__ d) {
  int i = blockIdx.x * 256 + threadIdx.x;       // 0 .. 2097151 float4 units
  const float* s;
  int off;
  if (i < 1048576)      { s = x;  off = i; }
  else if (i < 1835008) { s = wq; off = i - 1048576; }
  else                  { s = wp; off = i - 1835008; }
  float4 v = ((const float4*)s)[off];
  ushort4 o;
  o.x = f2bf(v.x); o.y = f2bf(v.y); o.z = f2bf(v.z); o.w = f2bf(v.w);
  ((ushort4*)d)[i] = o;
}

// ---------------- generic NT bf16 GEMM (proj) ----------------
template<int BM, int BN, int WM, int WN>
__global__ __launch_bounds__(256) void k_gemm(
    const unsigned short* __restrict__ A, const unsigned short* __restrict__ B,
    const float* __restrict__ bias, float* __restrict__ C, int M, int N, int K)
{
  constexpr int FM = BM / WM / 16;
  constexpr int FN = BN / WN / 16;
  __shared__ unsigned short lA[BM * 64];
  __shared__ unsigned short lB[BN * 64];
  int tid = threadIdx.x;
  int lane = tid & 63, wid = tid >> 6;
  int lg = lane >> 4, lo = lane & 15;
  int wm = wid / WN, wn = wid % WN;
  int m0 = blockIdx.y * BM, n0 = blockIdx.x * BN;

  f32x4 acc[FM][FN];
#pragma unroll
  for (int i = 0; i < FM; ++i)
#pragma unroll
    for (int j = 0; j < FN; ++j) acc[i][j] = (f32x4){0.f, 0.f, 0.f, 0.f};

  const int srow = tid >> 3, scol = (tid & 7) * 8;

  for (int kt = 0; kt < K; kt += 64) {
    __syncthreads();
#pragma unroll
    for (int i = 0; i < BM / 32; ++i)
      gld_lds16(A + (size_t)(m0 + srow + 32 * i) * K + kt + scol,
                &lA[(srow + 32 * i) * 64 + scol]);
#pragma unroll
    for (int i = 0; i < BN / 32; ++i)
      gld_lds16(B + (size_t)(n0 + srow + 32 * i) * K + kt + scol,
                &lB[(srow + 32 * i) * 64 + scol]);
    __syncthreads();

#pragma unroll
    for (int ks = 0; ks < 2; ++ks) {
      bf16x8 af[FM], bfr[FN];
#pragma unroll
      for (int i = 0; i < FM; ++i)
        af[i] = *(const bf16x8*)&lA[(wm * (BM / WM) + i * 16 + lo) * 64 + ks * 32 + lg * 8];
#pragma unroll
      for (int j = 0; j < FN; ++j)
        bfr[j] = *(const bf16x8*)&lB[(wn * (BN / WN) + j * 16 + lo) * 64 + ks * 32 + lg * 8];
      __builtin_amdgcn_s_setprio(1);
#pragma unroll
      for (int i = 0; i < FM; ++i)
#pragma unroll
        for (int j = 0; j < FN; ++j)
          acc[i][j] = __builtin_amdgcn_mfma_f32_16x16x32_bf16(af[i], bfr[j], acc[i][j], 0, 0, 0);
      __builtin_amdgcn_s_setprio(0);
    }
  }

#pragma unroll
  for (int j = 0; j < FN; ++j) {
    int col = n0 + wn * (BN / WN) + j * 16 + lo;
    float bb = bias[col];
#pragma unroll
    for (int i = 0; i < FM; ++i)
#pragma unroll
      for (int r = 0; r < 4; ++r) {
        int row = m0 + wm * (BM / WM) + i * 16 + lg * 4 + r;
        C[(size_t)row * N + col] = acc[i][j][r] + bb;
      }
  }
}

// ---------------- QKV GEMM with fused LN + split + V frag-major (unchanged) ----------------
__global__ __launch_bounds__(256) void k_gemm_qkv(
    const unsigned short* __restrict__ A,   // x_bf [4096][1024]
    const unsigned short* __restrict__ B,   // wq_bf [3072][1024]
    const float* __restrict__ bias,         // [3072]
    const float* __restrict__ qg, const float* __restrict__ qb,
    const float* __restrict__ kg, const float* __restrict__ kb,
    unsigned short* __restrict__ qh,        // [32][2048][64]
    unsigned short* __restrict__ kh,        // [32][2048][64]
    unsigned short* __restrict__ vf)        // [32][131072] frag-major
{
  __shared__ unsigned short lA[128 * 64];
  __shared__ unsigned short lB[128 * 64];
  int tid = threadIdx.x;
  int lane = tid & 63, wid = tid >> 6;
  int lg = lane >> 4, lo = lane & 15;
  int wm = wid >> 1, wn = wid & 1;
  int m0 = blockIdx.y * 128, n0 = blockIdx.x * 128;
  const int K = 1024;

  f32x4 acc[4][4];
#pragma unroll
  for (int i = 0; i < 4; ++i)
#pragma unroll
    for (int j = 0; j < 4; ++j) acc[i][j] = (f32x4){0.f, 0.f, 0.f, 0.f};

  const int srow = tid >> 3, scol = (tid & 7) * 8;

  for (int kt = 0; kt < K; kt += 64) {
    __syncthreads();
#pragma unroll
    for (int i = 0; i < 4; ++i)
      gld_lds16(A + (size_t)(m0 + srow + 32 * i) * K + kt + scol,
                &lA[(srow + 32 * i) * 64 + scol]);
#pragma unroll
    for (int i = 0; i < 4; ++i)
      gld_lds16(B + (size_t)(n0 + srow + 32 * i) * K + kt + scol,
                &lB[(srow + 32 * i) * 64 + scol]);
    __syncthreads();

#pragma unroll
    for (int ks = 0; ks < 2; ++ks) {
      bf16x8 af[4], bfr[4];
#pragma unroll
      for (int i = 0; i < 4; ++i)
        af[i] = *(const bf16x8*)&lA[(wm * 64 + i * 16 + lo) * 64 + ks * 32 + lg * 8];
#pragma unroll
      for (int j = 0; j < 4; ++j)
        bfr[j] = *(const bf16x8*)&lB[(wn * 64 + j * 16 + lo) * 64 + ks * 32 + lg * 8];
      __builtin_amdgcn_s_setprio(1);
#pragma unroll
      for (int i = 0; i < 4; ++i)
#pragma unroll
        for (int j = 0; j < 4; ++j)
          acc[i][j] = __builtin_amdgcn_mfma_f32_16x16x32_bf16(af[i], bfr[j], acc[i][j], 0, 0, 0);
      __builtin_amdgcn_s_setprio(0);
    }
  }

  // ---- fused epilogue ----
  int m0b = m0 & 2047;
  int bb_ = m0 >> 11;
  int hcol = (n0 + wn * 64) >> 6;      // 0..15 q, 16..31 k, 32..47 v
  float bias4[4];
#pragma unroll
  for (int j = 0; j < 4; ++j) bias4[j] = bias[n0 + wn * 64 + j * 16 + lo];

  if (hcol >= 32) {
    int bh = bb_ * 16 + (hcol - 32);
    int T = m0b >> 7;
    int hi_ = lg >> 1;
    int j8b = (lg & 1) * 4;
    unsigned short* vbase = vf + (size_t)bh * 131072 + T * 8192 + hi_ * 256 + j8b;
#pragma unroll
    for (int i = 0; i < 4; ++i) {
      int ss = wm * 4 + i;
#pragma unroll
      for (int j = 0; j < 4; ++j) {
        int dh = j >> 1, dp = (j & 1) * 16 + lo;
        uint2 w;
        w.x = pkbf(acc[i][j][0] + bias4[j], acc[i][j][1] + bias4[j]);
        w.y = pkbf(acc[i][j][2] + bias4[j], acc[i][j][3] + bias4[j]);
        *(uint2*)(vbase + ss * 1024 + dh * 512 + dp * 8) = w;
      }
    }
  } else {
    bool isq = hcol < 16;
    int bh = bb_ * 16 + (isq ? hcol : hcol - 16);
    const float* g = isq ? qg : kg;
    const float* bt = isq ? qb : kb;
    float osc = isq ? 0.18033688f : 1.0f;   // 0.125 * log2(e) folded into q
    float g4[4], t4[4];
#pragma unroll
    for (int j = 0; j < 4; ++j) {
      g4[j] = g[j * 16 + lo] * osc;
      t4[j] = bt[j * 16 + lo] * osc;
    }
    unsigned short* dst = (isq ? qh : kh) + (size_t)bh * 131072;
#pragma unroll
    for (int i = 0; i < 4; ++i) {
#pragma unroll
      for (int r = 0; r < 4; ++r) {
        float v0 = acc[i][0][r] + bias4[0];
        float v1 = acc[i][1][r] + bias4[1];
        float v2 = acc[i][2][r] + bias4[2];
        float v3 = acc[i][3][r] + bias4[3];
        float sm = (v0 + v1) + (v2 + v3);
        sm += __shfl_xor(sm, 1, 64); sm += __shfl_xor(sm, 2, 64);
        sm += __shfl_xor(sm, 4, 64); sm += __shfl_xor(sm, 8, 64);
        float mu = sm * (1.0f / 64.0f);
        float d0 = v0 - mu, d1 = v1 - mu, d2 = v2 - mu, d3 = v3 - mu;
        float vv = (d0 * d0 + d1 * d1) + (d2 * d2 + d3 * d3);
        vv += __shfl_xor(vv, 1, 64); vv += __shfl_xor(vv, 2, 64);
        vv += __shfl_xor(vv, 4, 64); vv += __shfl_xor(vv, 8, 64);
        float rs = rsqrtf(vv * (1.0f / 64.0f) + 1e-5f);
        int s = m0b + wm * 64 + i * 16 + lg * 4 + r;
        unsigned short* row = dst + (size_t)s * 64 + lo;
        row[0]  = f2bf(fmaf(d0 * rs, g4[0], t4[0]));
        row[16] = f2bf(fmaf(d1 * rs, g4[1], t4[1]));
        row[32] = f2bf(fmaf(d2 * rs, g4[2], t4[2]));
        row[48] = f2bf(fmaf(d3 * rs, g4[3], t4[3]));
      }
    }
  }
}

// ==================== attention v11 helpers ====================

// stage one 16KB tile-pair into LDS buffer (XOR-swizzled global source)
__device__ __forceinline__ void stage_pair(const char* kbytes, int pair,
                                           char* dst, int tid) {
#pragma unroll
  for (int ii = 0; ii < 4; ++ii) {
    int b = ii * 4096 + tid * 16;
    int sb = b ^ (((b >> 7) & 7) << 4);      // involution (bits 4-6)
    gld_lds16(kbytes + (size_t)pair * 16384 + sb, dst + b);
  }
}

// QK^T for this wave's 64-kv tile out of an LDS buffer -> sc (zero-frag init)
__device__ __forceinline__ void qk_body(f32x16 (&sc)[2], const char* lKbuf,
                                        int g, int l31, int hi,
                                        const bf16x8 (&qf)[4], const f32x16& z16) {
  const char* bK = lKbuf + g * 8192;
  __builtin_amdgcn_s_setprio(1);
#pragma unroll
  for (int c = 0; c < 2; ++c) {
    int row = c * 32 + l31;
    int rx = (row * 128) ^ ((row & 7) << 4);
    bf16x8 kf = *(const bf16x8*)(bK + (rx ^ (hi * 16)));
    sc[c] = __builtin_amdgcn_mfma_f32_32x32x16_bf16(kf, qf[0], z16, 0, 0, 0);
#pragma unroll
    for (int s = 1; s < 4; ++s) {
      kf = *(const bf16x8*)(bK + (rx ^ ((2 * s + hi) * 16)));
      sc[c] = __builtin_amdgcn_mfma_f32_32x32x16_bf16(kf, qf[s], sc[c], 0, 0, 0);
    }
  }
  __builtin_amdgcn_s_setprio(0);
}

// softmax + PV for a previously-computed score set (V loaded in-loop from L2)
__device__ __forceinline__ void smpv_body(f32x16 (&sc)[2],
                                          const unsigned short* vt,
                                          float& m, float& lsum,
                                          f32x16& o0, f32x16& o1) {
  // max tree (max3-fusable)
  float r[8];
#pragma unroll
  for (int i2 = 0; i2 < 8; ++i2)
    r[i2] = fmaxf(fmaxf(sc[0][i2], sc[0][i2 + 8]),
                  fmaxf(sc[1][i2], sc[1][i2 + 8]));
  float pm = fmaxf(fmaxf(fmaxf(r[0], r[1]), fmaxf(r[2], r[3])),
                   fmaxf(fmaxf(r[4], r[5]), fmaxf(r[6], r[7])));
  pm = fmaxf(pm, __shfl_xor(pm, 32, 64));

  if (!__all(pm - m <= 8.0f)) {              // defer-max
    float mn = fmaxf(m, pm);
    float fac = fexp2(m - mn);
    m = mn;
    lsum *= fac;
#pragma unroll
    for (int i2 = 0; i2 < 16; ++i2) { o0[i2] *= fac; o1[i2] *= fac; }
  }

  // raw-rate exp2 + tree sum
#pragma unroll
  for (int c = 0; c < 2; ++c)
#pragma unroll
    for (int i2 = 0; i2 < 16; ++i2) sc[c][i2] = fexp2(sc[c][i2] - m);
  float ts[16];
#pragma unroll
  for (int i2 = 0; i2 < 16; ++i2) ts[i2] = sc[0][i2] + sc[1][i2];
#pragma unroll
  for (int d = 8; d; d >>= 1)
#pragma unroll
    for (int i2 = 0; i2 < d; ++i2) ts[i2] += ts[i2 + d];
  lsum += ts[0] + __shfl_xor(ts[0], 32, 64);

  // PV: 4 s-steps of 16 kv; V loaded in-loop (r9 placement, proven)
#pragma unroll
  for (int s = 0; s < 4; ++s) {
    const f32x16& sf = sc[s >> 1];
    const int rb = (s & 1) * 8;
    unsigned d0 = pkbf(sf[rb + 0], sf[rb + 1]);
    unsigned d1 = pkbf(sf[rb + 2], sf[rb + 3]);
    unsigned d2 = pkbf(sf[rb + 4], sf[rb + 5]);
    unsigned d3 = pkbf(sf[rb + 6], sf[rb + 7]);
    pl32swap(d0, d2);
    pl32swap(d1, d3);
    union { unsigned u[4]; bf16x8 v; } pu;
    pu.u[0] = d0; pu.u[1] = d1; pu.u[2] = d2; pu.u[3] = d3;
    bf16x8 v0 = *(const bf16x8*)(vt + s * 1024);
    bf16x8 v1 = *(const bf16x8*)(vt + s * 1024 + 512);
    __builtin_amdgcn_s_setprio(1);
    o0 = __builtin_amdgcn_mfma_f32_32x32x16_bf16(v0, pu.v, o0, 0, 0, 0);
    o1 = __builtin_amdgcn_mfma_f32_32x32x16_bf16(v1, pu.v, o1, 0, 0, 0);
    __builtin_amdgcn_s_setprio(0);
  }
}

// ---------------- flash attention v11: T15 double-pipeline ----------------
// Per iteration: QK(tile i) -> one score set while softmax+PV(tile i-1) runs
// from the other. Two named score sets, explicit 2x-unrolled role swap.
__global__ __launch_bounds__(256, 3) void k_attn(
    const unsigned short* __restrict__ Q,   // [BH][S][64] (pre-scaled)
    const unsigned short* __restrict__ K,   // [BH][S][64]
    const unsigned short* __restrict__ VF,  // [BH][131072] frag-major
    unsigned short* __restrict__ O)         // [B*S][1024] bf16
{
  __shared__ char lK[2][16384];   // 32 KB: [buf][g*8192 + row*128 + col]

  int tid = threadIdx.x;
  int wid = tid >> 6, lane = tid & 63;
  int l31 = lane & 31, hi = lane >> 5;
  int qc = wid >> 1, g = wid & 1;

  int id = blockIdx.x;                       // 1024 blocks, XCD-bijective
  int nid = (id & 7) * 128 + (id >> 3);
  int bh = nid >> 5;
  int q0 = (nid & 31) << 6;                  // 64 q-rows per block
  int q = q0 + qc * 32 + l31;

  const unsigned short* qp = Q + ((size_t)bh * 2048 + q) * 64 + hi * 8;
  bf16x8 qf[4];
#pragma unroll
  for (int s = 0; s < 4; ++s) qf[s] = *(const bf16x8*)(qp + 16 * s);

  const char* kbytes = (const char*)(K + (size_t)bh * 131072);
  const unsigned short* vfb = VF + (size_t)bh * 131072 + lane * 8;

  f32x16 z16;
#pragma unroll
  for (int i = 0; i < 16; ++i) z16[i] = 0.f;
  float m = -1e30f, lsum = 0.0f;
  f32x16 o0 = z16, o1 = z16;

  f32x16 scA[2], scB[2];

  // prologue: stage pair 0, then pair 1; QK(T_g) -> A
  stage_pair(kbytes, 0, lK[0], tid);
  __syncthreads();
  stage_pair(kbytes, 1, lK[1], tid);
  qk_body(scA, lK[0], g, l31, hi, qf, z16);
  __syncthreads();

  // steady state: 7 double-iterations cover iters 1..14
#pragma unroll 1
  for (int ii = 0; ii < 7; ++ii) {
    // iter 2ii+1: QK from buf1 -> B; SMPV(A) = tile 4ii+g
    stage_pair(kbytes, 2 * ii + 2, lK[0], tid);
    qk_body(scB, lK[1], g, l31, hi, qf, z16);
    smpv_body(scA, vfb + (size_t)(4 * ii + g) * 4096, m, lsum, o0, o1);
    __syncthreads();
    // iter 2ii+2: QK from buf0 -> A; SMPV(B) = tile 4ii+2+g
    stage_pair(kbytes, 2 * ii + 3, lK[1], tid);
    qk_body(scA, lK[0], g, l31, hi, qf, z16);
    smpv_body(scB, vfb + (size_t)(4 * ii + 2 + g) * 4096, m, lsum, o0, o1);
    __syncthreads();
  }

  // iter 15: QK(T_15) from buf1 -> B; SMPV(A) = tile 28+g
  qk_body(scB, lK[1], g, l31, hi, qf, z16);
  smpv_body(scA, vfb + (size_t)(28 + g) * 4096, m, lsum, o0, o1);
  // tail: SMPV(B) = tile 30+g
  smpv_body(scB, vfb + (size_t)(30 + g) * 4096, m, lsum, o0, o1);

  // ---- kv-group merge via LDS (lK[0] safe: last read was iter 14, barriered) ----
  float* mb = (float*)&lK[0][0];
  int base = (qc * 64 + lane) * 34;
  if (g) {
#pragma unroll
    for (int i2 = 0; i2 < 16; ++i2) { mb[base + i2] = o0[i2]; mb[base + 16 + i2] = o1[i2]; }
    mb[base + 32] = m; mb[base + 33] = lsum;
  }
  __syncthreads();
  if (!g) {
    float m1 = mb[base + 32], l1 = mb[base + 33];
    float mn = fmaxf(m, m1);
    float f0 = fexp2(m - mn), f1 = fexp2(m1 - mn);
    float linv = 1.0f / (lsum * f0 + l1 * f1);
    float a0 = f0 * linv, a1 = f1 * linv;
    int b = bh >> 4, h = bh & 15;
    unsigned short* ob = O + ((size_t)(b * 2048 + q)) * 1024 + h * 64;
#pragma unroll
    for (int gg = 0; gg < 4; ++gg) {
      uint2 w;
      w.x = pkbf(o0[4 * gg + 0] * a0 + mb[base + 4 * gg + 0] * a1,
                 o0[4 * gg + 1] * a0 + mb[base + 4 * gg + 1] * a1);
      w.y = pkbf(o0[4 * gg + 2] * a0 + mb[base + 4 * gg + 2] * a1,
                 o0[4 * gg + 3] * a0 + mb[base + 4 * gg + 3] * a1);
      *(uint2*)(ob + 8 * gg + 4 * hi) = w;
      w.x = pkbf(o1[4 * gg + 0] * a0 + mb[base + 16 + 4 * gg + 0] * a1,
                 o1[4 * gg + 1] * a0 + mb[base + 16 + 4 * gg + 1] * a1);
      w.y = pkbf(o1[4 * gg + 2] * a0 + mb[base + 16 + 4 * gg + 2] * a1,
                 o1[4 * gg + 3] * a0 + mb[base + 16 + 4 * gg + 3] * a1);
      *(uint2*)(ob + 32 + 8 * gg + 4 * hi) = w;
    }
  }
}

extern "C" void kernel_launch(void* const* d_in, const int* in_sizes, int n_in,
                              void* d_out, int out_size, void* d_ws, size_t ws_size,
                              hipStream_t stream)
{
  (void)in_sizes; (void)n_in; (void)out_size; (void)ws_size;
  const float* x      = (const float*)d_in[0];
  const float* w_qkv  = (const float*)d_in[1];
  const float* b_qkv  = (const float*)d_in[2];
  const float* w_proj = (const float*)d_in[3];
  const float* b_proj = (const float*)d_in[4];
  const float* q_g    = (const float*)d_in[5];
  const float* q_b    = (const float*)d_in[6];
  const float* k_g    = (const float*)d_in[7];
  const float* k_b    = (const float*)d_in[8];
  float* out = (float*)d_out;

  char* p = (char*)d_ws;
  unsigned short* x_bf  = (unsigned short*)p;  p += (size_t)4096 * 1024 * 2;
  unsigned short* wq_bf = (unsigned short*)p;  p += (size_t)3072 * 1024 * 2;
  unsigned short* wp_bf = (unsigned short*)p;  p += (size_t)1024 * 1024 * 2;
  unsigned short* qh    = (unsigned short*)p;  p += (size_t)32 * 2048 * 64 * 2;
  unsigned short* kh    = (unsigned short*)p;  p += (size_t)32 * 2048 * 64 * 2;
  unsigned short* vfr   = (unsigned short*)p;  p += (size_t)32 * 131072 * 2;
  unsigned short* ao    = (unsigned short*)p;  p += (size_t)4096 * 1024 * 2;

  k_cvt3<<<8192, 256, 0, stream>>>(x, w_qkv, w_proj, x_bf);

  k_gemm_qkv<<<dim3(24, 32), 256, 0, stream>>>(x_bf, wq_bf, b_qkv,
                                               q_g, q_b, k_g, k_b, qh, kh, vfr);
  k_attn<<<1024, 256, 0, stream>>>(qh, kh, vfr, ao);
  k_gemm<64, 128, 1, 4><<<dim3(8, 64), 256, 0, stream>>>(ao, wp_bf, b_proj, out, 4096, 1024, 1024);
}

// Round 15
// 154.147 us; speedup vs baseline: 1.0014x; 1.0008x over previous
//
#include <hip/hip_runtime.h>
#include <hip/hip_bf16.h>

// B=2, S=2048, D=1024, H=16, Hd=64
// cvt(fused) -> QKV GEMM + fused LN/split/V-frag-major epilogue ->
// flash attention (swapped-QK, kv-split 2x, T15 double-pipeline:
// QK(cur) || softmax+PV(prev)) -> proj GEMM

typedef __attribute__((ext_vector_type(8)))  short bf16x8;   // 8 bf16 (4 VGPRs)
typedef __attribute__((ext_vector_type(4)))  float f32x4;
typedef __attribute__((ext_vector_type(16))) float f32x16;

__device__ __forceinline__ unsigned short f2bf(float f) {
  union { float f; unsigned u; } v; v.f = f;
  unsigned r = v.u + 0x7FFFu + ((v.u >> 16) & 1u);
  return (unsigned short)(r >> 16);
}

__device__ __forceinline__ unsigned pkbf(float a, float b) {
  unsigned r;
  asm("v_cvt_pk_bf16_f32 %0, %1, %2" : "=v"(r) : "v"(a), "v"(b));
  return r;
}

__device__ __forceinline__ void pl32swap(unsigned& x, unsigned& y) {
  asm("v_permlane32_swap_b32 %0, %1" : "+v"(x), "+v"(y));
}

// raw-rate exp2 (args bounded by defer-max; denormal flush-to-0 fine here)
__device__ __forceinline__ float fexp2(float x) {
  float r; asm("v_exp_f32 %0, %1" : "=v"(r) : "v"(x)); return r;
}

__device__ __forceinline__ void gld_lds16(const void* g, void* l) {
  __builtin_amdgcn_global_load_lds(
      (const __attribute__((address_space(1))) void*)g,
      (__attribute__((address_space(3))) void*)l, 16, 0, 0);
}

// ---------------- fused fp32 -> bf16 convert ----------------
__global__ __launch_bounds__(256) void k_cvt3(const float* __restrict__ x,
                                              const float* __restrict__ wq,
                                              const float* __restrict__ wp,
                                              unsigned short* __restrict__ d) {
  int i = blockIdx.x * 256 + threadIdx.x;       // 0 .. 2097151 float4 units
  const float* s;
  int off;
  if (i < 1048576)      { s = x;  off = i; }
  else if (i < 1835008) { s = wq; off = i - 1048576; }
  else                  { s = wp; off = i - 1835008; }
  float4 v = ((const float4*)s)[off];
  ushort4 o;
  o.x = f2bf(v.x); o.y = f2bf(v.y); o.z = f2bf(v.z); o.w = f2bf(v.w);
  ((ushort4*)d)[i] = o;
}

// ---------------- generic NT bf16 GEMM (proj) ----------------
template<int BM, int BN, int WM, int WN>
__global__ __launch_bounds__(256) void k_gemm(
    const unsigned short* __restrict__ A, const unsigned short* __restrict__ B,
    const float* __restrict__ bias, float* __restrict__ C, int M, int N, int K)
{
  constexpr int FM = BM / WM / 16;
  constexpr int FN = BN / WN / 16;
  __shared__ unsigned short lA[BM * 64];
  __shared__ unsigned short lB[BN * 64];
  int tid = threadIdx.x;
  int lane = tid & 63, wid = tid >> 6;
  int lg = lane >> 4, lo = lane & 15;
  int wm = wid / WN, wn = wid % WN;
  int m0 = blockIdx.y * BM, n0 = blockIdx.x * BN;

  f32x4 acc[FM][FN];
#pragma unroll
  for (int i = 0; i < FM; ++i)
#pragma unroll
    for (int j = 0; j < FN; ++j) acc[i][j] = (f32x4){0.f, 0.f, 0.f, 0.f};

  const int srow = tid >> 3, scol = (tid & 7) * 8;

  for (int kt = 0; kt < K; kt += 64) {
    __syncthreads();
#pragma unroll
    for (int i = 0; i < BM / 32; ++i)
      gld_lds16(A + (size_t)(m0 + srow + 32 * i) * K + kt + scol,
                &lA[(srow + 32 * i) * 64 + scol]);
#pragma unroll
    for (int i = 0; i < BN / 32; ++i)
      gld_lds16(B + (size_t)(n0 + srow + 32 * i) * K + kt + scol,
                &lB[(srow + 32 * i) * 64 + scol]);
    __syncthreads();

#pragma unroll
    for (int ks = 0; ks < 2; ++ks) {
      bf16x8 af[FM], bfr[FN];
#pragma unroll
      for (int i = 0; i < FM; ++i)
        af[i] = *(const bf16x8*)&lA[(wm * (BM / WM) + i * 16 + lo) * 64 + ks * 32 + lg * 8];
#pragma unroll
      for (int j = 0; j < FN; ++j)
        bfr[j] = *(const bf16x8*)&lB[(wn * (BN / WN) + j * 16 + lo) * 64 + ks * 32 + lg * 8];
      __builtin_amdgcn_s_setprio(1);
#pragma unroll
      for (int i = 0; i < FM; ++i)
#pragma unroll
        for (int j = 0; j < FN; ++j)
          acc[i][j] = __builtin_amdgcn_mfma_f32_16x16x32_bf16(af[i], bfr[j], acc[i][j], 0, 0, 0);
      __builtin_amdgcn_s_setprio(0);
    }
  }

#pragma unroll
  for (int j = 0; j < FN; ++j) {
    int col = n0 + wn * (BN / WN) + j * 16 + lo;
    float bb = bias[col];
#pragma unroll
    for (int i = 0; i < FM; ++i)
#pragma unroll
      for (int r = 0; r < 4; ++r) {
        int row = m0 + wm * (BM / WM) + i * 16 + lg * 4 + r;
        C[(size_t)row * N + col] = acc[i][j][r] + bb;
      }
  }
}

// ---------------- QKV GEMM with fused LN + split + V frag-major (unchanged) ----------------
__global__ __launch_bounds__(256) void k_gemm_qkv(
    const unsigned short* __restrict__ A,   // x_bf [4096][1024]
    const unsigned short* __restrict__ B,   // wq_bf [3072][1024]
    const float* __restrict__ bias,         // [3072]
    const float* __restrict__ qg, const float* __restrict__ qb,
    const float* __restrict__ kg, const float* __restrict__ kb,
    unsigned short* __restrict__ qh,        // [32][2048][64]
    unsigned short* __restrict__ kh,        // [32][2048][64]
    unsigned short* __restrict__ vf)        // [32][131072] frag-major
{
  __shared__ unsigned short lA[128 * 64];
  __shared__ unsigned short lB[128 * 64];
  int tid = threadIdx.x;
  int lane = tid & 63, wid = tid >> 6;
  int lg = lane >> 4, lo = lane & 15;
  int wm = wid >> 1, wn = wid & 1;
  int m0 = blockIdx.y * 128, n0 = blockIdx.x * 128;
  const int K = 1024;

  f32x4 acc[4][4];
#pragma unroll
  for (int i = 0; i < 4; ++i)
#pragma unroll
    for (int j = 0; j < 4; ++j) acc[i][j] = (f32x4){0.f, 0.f, 0.f, 0.f};

  const int srow = tid >> 3, scol = (tid & 7) * 8;

  for (int kt = 0; kt < K; kt += 64) {
    __syncthreads();
#pragma unroll
    for (int i = 0; i < 4; ++i)
      gld_lds16(A + (size_t)(m0 + srow + 32 * i) * K + kt + scol,
                &lA[(srow + 32 * i) * 64 + scol]);
#pragma unroll
    for (int i = 0; i < 4; ++i)
      gld_lds16(B + (size_t)(n0 + srow + 32 * i) * K + kt + scol,
                &lB[(srow + 32 * i) * 64 + scol]);
    __syncthreads();

#pragma unroll
    for (int ks = 0; ks < 2; ++ks) {
      bf16x8 af[4], bfr[4];
#pragma unroll
      for (int i = 0; i < 4; ++i)
        af[i] = *(const bf16x8*)&lA[(wm * 64 + i * 16 + lo) * 64 + ks * 32 + lg * 8];
#pragma unroll
      for (int j = 0; j < 4; ++j)
        bfr[j] = *(const bf16x8*)&lB[(wn * 64 + j * 16 + lo) * 64 + ks * 32 + lg * 8];
      __builtin_amdgcn_s_setprio(1);
#pragma unroll
      for (int i = 0; i < 4; ++i)
#pragma unroll
        for (int j = 0; j < 4; ++j)
          acc[i][j] = __builtin_amdgcn_mfma_f32_16x16x32_bf16(af[i], bfr[j], acc[i][j], 0, 0, 0);
      __builtin_amdgcn_s_setprio(0);
    }
  }

  // ---- fused epilogue ----
  int m0b = m0 & 2047;
  int bb_ = m0 >> 11;
  int hcol = (n0 + wn * 64) >> 6;      // 0..15 q, 16..31 k, 32..47 v
  float bias4[4];
#pragma unroll
  for (int j = 0; j < 4; ++j) bias4[j] = bias[n0 + wn * 64 + j * 16 + lo];

  if (hcol >= 32) {
    int bh = bb_ * 16 + (hcol - 32);
    int T = m0b >> 7;
    int hi_ = lg >> 1;
    int j8b = (lg & 1) * 4;
    unsigned short* vbase = vf + (size_t)bh * 131072 + T * 8192 + hi_ * 256 + j8b;
#pragma unroll
    for (int i = 0; i < 4; ++i) {
      int ss = wm * 4 + i;
#pragma unroll
      for (int j = 0; j < 4; ++j) {
        int dh = j >> 1, dp = (j & 1) * 16 + lo;
        uint2 w;
        w.x = pkbf(acc[i][j][0] + bias4[j], acc[i][j][1] + bias4[j]);
        w.y = pkbf(acc[i][j][2] + bias4[j], acc[i][j][3] + bias4[j]);
        *(uint2*)(vbase + ss * 1024 + dh * 512 + dp * 8) = w;
      }
    }
  } else {
    bool isq = hcol < 16;
    int bh = bb_ * 16 + (isq ? hcol : hcol - 16);
    const float* g = isq ? qg : kg;
    const float* bt = isq ? qb : kb;
    float osc = isq ? 0.18033688f : 1.0f;   // 0.125 * log2(e) folded into q
    float g4[4], t4[4];
#pragma unroll
    for (int j = 0; j < 4; ++j) {
      g4[j] = g[j * 16 + lo] * osc;
      t4[j] = bt[j * 16 + lo] * osc;
    }
    unsigned short* dst = (isq ? qh : kh) + (size_t)bh * 131072;
#pragma unroll
    for (int i = 0; i < 4; ++i) {
#pragma unroll
      for (int r = 0; r < 4; ++r) {
        float v0 = acc[i][0][r] + bias4[0];
        float v1 = acc[i][1][r] + bias4[1];
        float v2 = acc[i][2][r] + bias4[2];
        float v3 = acc[i][3][r] + bias4[3];
        float sm = (v0 + v1) + (v2 + v3);
        sm += __shfl_xor(sm, 1, 64); sm += __shfl_xor(sm, 2, 64);
        sm += __shfl_xor(sm, 4, 64); sm += __shfl_xor(sm, 8, 64);
        float mu = sm * (1.0f / 64.0f);
        float d0 = v0 - mu, d1 = v1 - mu, d2 = v2 - mu, d3 = v3 - mu;
        float vv = (d0 * d0 + d1 * d1) + (d2 * d2 + d3 * d3);
        vv += __shfl_xor(vv, 1, 64); vv += __shfl_xor(vv, 2, 64);
        vv += __shfl_xor(vv, 4, 64); vv += __shfl_xor(vv, 8, 64);
        float rs = rsqrtf(vv * (1.0f / 64.0f) + 1e-5f);
        int s = m0b + wm * 64 + i * 16 + lg * 4 + r;
        unsigned short* row = dst + (size_t)s * 64 + lo;
        row[0]  = f2bf(fmaf(d0 * rs, g4[0], t4[0]));
        row[16] = f2bf(fmaf(d1 * rs, g4[1], t4[1]));
        row[32] = f2bf(fmaf(d2 * rs, g4[2], t4[2]));
        row[48] = f2bf(fmaf(d3 * rs, g4[3], t4[3]));
      }
    }
  }
}

// ==================== attention v11 helpers ====================

// stage one 16KB tile-pair into LDS buffer (XOR-swizzled global source)
__device__ __forceinline__ void stage_pair(const char* kbytes, int pair,
                                           char* dst, int tid) {
#pragma unroll
  for (int ii = 0; ii < 4; ++ii) {
    int b = ii * 4096 + tid * 16;
    int sb = b ^ (((b >> 7) & 7) << 4);      // involution (bits 4-6)
    gld_lds16(kbytes + (size_t)pair * 16384 + sb, dst + b);
  }
}

// QK^T for this wave's 64-kv tile out of an LDS buffer -> sc (zero-frag init)
__device__ __forceinline__ void qk_body(f32x16 (&sc)[2], const char* lKbuf,
                                        int g, int l31, int hi,
                                        const bf16x8 (&qf)[4], const f32x16& z16) {
  const char* bK = lKbuf + g * 8192;
  __builtin_amdgcn_s_setprio(1);
#pragma unroll
  for (int c = 0; c < 2; ++c) {
    int row = c * 32 + l31;
    int rx = (row * 128) ^ ((row & 7) << 4);
    bf16x8 kf = *(const bf16x8*)(bK + (rx ^ (hi * 16)));
    sc[c] = __builtin_amdgcn_mfma_f32_32x32x16_bf16(kf, qf[0], z16, 0, 0, 0);
#pragma unroll
    for (int s = 1; s < 4; ++s) {
      kf = *(const bf16x8*)(bK + (rx ^ ((2 * s + hi) * 16)));
      sc[c] = __builtin_amdgcn_mfma_f32_32x32x16_bf16(kf, qf[s], sc[c], 0, 0, 0);
    }
  }
  __builtin_amdgcn_s_setprio(0);
}

// softmax + PV for a previously-computed score set (V loaded in-loop from L2)
__device__ __forceinline__ void smpv_body(f32x16 (&sc)[2],
                                          const unsigned short* vt,
                                          float& m, float& lsum,
                                          f32x16& o0, f32x16& o1) {
  // max tree (max3-fusable)
  float r[8];
#pragma unroll
  for (int i2 = 0; i2 < 8; ++i2)
    r[i2] = fmaxf(fmaxf(sc[0][i2], sc[0][i2 + 8]),
                  fmaxf(sc[1][i2], sc[1][i2 + 8]));
  float pm = fmaxf(fmaxf(fmaxf(r[0], r[1]), fmaxf(r[2], r[3])),
                   fmaxf(fmaxf(r[4], r[5]), fmaxf(r[6], r[7])));
  pm = fmaxf(pm, __shfl_xor(pm, 32, 64));

  if (!__all(pm - m <= 8.0f)) {              // defer-max
    float mn = fmaxf(m, pm);
    float fac = fexp2(m - mn);
    m = mn;
    lsum *= fac;
#pragma unroll
    for (int i2 = 0; i2 < 16; ++i2) { o0[i2] *= fac; o1[i2] *= fac; }
  }

  // raw-rate exp2 + tree sum
#pragma unroll
  for (int c = 0; c < 2; ++c)
#pragma unroll
    for (int i2 = 0; i2 < 16; ++i2) sc[c][i2] = fexp2(sc[c][i2] - m);
  float ts[16];
#pragma unroll
  for (int i2 = 0; i2 < 16; ++i2) ts[i2] = sc[0][i2] + sc[1][i2];
#pragma unroll
  for (int d = 8; d; d >>= 1)
#pragma unroll
    for (int i2 = 0; i2 < d; ++i2) ts[i2] += ts[i2 + d];
  lsum += ts[0] + __shfl_xor(ts[0], 32, 64);

  // PV: 4 s-steps of 16 kv; V loaded in-loop (r9 placement, proven)
#pragma unroll
  for (int s = 0; s < 4; ++s) {
    const f32x16& sf = sc[s >> 1];
    const int rb = (s & 1) * 8;
    unsigned d0 = pkbf(sf[rb + 0], sf[rb + 1]);
    unsigned d1 = pkbf(sf[rb + 2], sf[rb + 3]);
    unsigned d2 = pkbf(sf[rb + 4], sf[rb + 5]);
    unsigned d3 = pkbf(sf[rb + 6], sf[rb + 7]);
    pl32swap(d0, d2);
    pl32swap(d1, d3);
    union { unsigned u[4]; bf16x8 v; } pu;
    pu.u[0] = d0; pu.u[1] = d1; pu.u[2] = d2; pu.u[3] = d3;
    bf16x8 v0 = *(const bf16x8*)(vt + s * 1024);
    bf16x8 v1 = *(const bf16x8*)(vt + s * 1024 + 512);
    __builtin_amdgcn_s_setprio(1);
    o0 = __builtin_amdgcn_mfma_f32_32x32x16_bf16(v0, pu.v, o0, 0, 0, 0);
    o1 = __builtin_amdgcn_mfma_f32_32x32x16_bf16(v1, pu.v, o1, 0, 0, 0);
    __builtin_amdgcn_s_setprio(0);
  }
}

// ---------------- flash attention v11: T15 double-pipeline ----------------
// Per iteration: QK(tile i) -> one score set while softmax+PV(tile i-1) runs
// from the other. Two named score sets, explicit 2x-unrolled role swap.
__global__ __launch_bounds__(256, 3) void k_attn(
    const unsigned short* __restrict__ Q,   // [BH][S][64] (pre-scaled)
    const unsigned short* __restrict__ K,   // [BH][S][64]
    const unsigned short* __restrict__ VF,  // [BH][131072] frag-major
    unsigned short* __restrict__ O)         // [B*S][1024] bf16
{
  __shared__ char lK[2][16384];   // 32 KB: [buf][g*8192 + row*128 + col]

  int tid = threadIdx.x;
  int wid = tid >> 6, lane = tid & 63;
  int l31 = lane & 31, hi = lane >> 5;
  int qc = wid >> 1, g = wid & 1;

  int id = blockIdx.x;                       // 1024 blocks, XCD-bijective
  int nid = (id & 7) * 128 + (id >> 3);
  int bh = nid >> 5;
  int q0 = (nid & 31) << 6;                  // 64 q-rows per block
  int q = q0 + qc * 32 + l31;

  const unsigned short* qp = Q + ((size_t)bh * 2048 + q) * 64 + hi * 8;
  bf16x8 qf[4];
#pragma unroll
  for (int s = 0; s < 4; ++s) qf[s] = *(const bf16x8*)(qp + 16 * s);

  const char* kbytes = (const char*)(K + (size_t)bh * 131072);
  const unsigned short* vfb = VF + (size_t)bh * 131072 + lane * 8;

  f32x16 z16;
#pragma unroll
  for (int i = 0; i < 16; ++i) z16[i] = 0.f;
  float m = -1e30f, lsum = 0.0f;
  f32x16 o0 = z16, o1 = z16;

  f32x16 scA[2], scB[2];

  // prologue: stage pair 0, then pair 1; QK(T_g) -> A
  stage_pair(kbytes, 0, lK[0], tid);
  __syncthreads();
  stage_pair(kbytes, 1, lK[1], tid);
  qk_body(scA, lK[0], g, l31, hi, qf, z16);
  __syncthreads();

  // steady state: 7 double-iterations cover iters 1..14
#pragma unroll 1
  for (int ii = 0; ii < 7; ++ii) {
    // iter 2ii+1: QK from buf1 -> B; SMPV(A) = tile 4ii+g
    stage_pair(kbytes, 2 * ii + 2, lK[0], tid);
    qk_body(scB, lK[1], g, l31, hi, qf, z16);
    smpv_body(scA, vfb + (size_t)(4 * ii + g) * 4096, m, lsum, o0, o1);
    __syncthreads();
    // iter 2ii+2: QK from buf0 -> A; SMPV(B) = tile 4ii+2+g
    stage_pair(kbytes, 2 * ii + 3, lK[1], tid);
    qk_body(scA, lK[0], g, l31, hi, qf, z16);
    smpv_body(scB, vfb + (size_t)(4 * ii + 2 + g) * 4096, m, lsum, o0, o1);
    __syncthreads();
  }

  // iter 15: QK(T_15) from buf1 -> B; SMPV(A) = tile 28+g
  qk_body(scB, lK[1], g, l31, hi, qf, z16);
  smpv_body(scA, vfb + (size_t)(28 + g) * 4096, m, lsum, o0, o1);
  // tail: SMPV(B) = tile 30+g
  smpv_body(scB, vfb + (size_t)(30 + g) * 4096, m, lsum, o0, o1);

  // ---- kv-group merge via LDS (lK[0] safe: last read was iter 14, barriered) ----
  float* mb = (float*)&lK[0][0];
  int base = (qc * 64 + lane) * 34;
  if (g) {
#pragma unroll
    for (int i2 = 0; i2 < 16; ++i2) { mb[base + i2] = o0[i2]; mb[base + 16 + i2] = o1[i2]; }
    mb[base + 32] = m; mb[base + 33] = lsum;
  }
  __syncthreads();
  if (!g) {
    float m1 = mb[base + 32], l1 = mb[base + 33];
    float mn = fmaxf(m, m1);
    float f0 = fexp2(m - mn), f1 = fexp2(m1 - mn);
    float linv = 1.0f / (lsum * f0 + l1 * f1);
    float a0 = f0 * linv, a1 = f1 * linv;
    int b = bh >> 4, h = bh & 15;
    unsigned short* ob = O + ((size_t)(b * 2048 + q)) * 1024 + h * 64;
#pragma unroll
    for (int gg = 0; gg < 4; ++gg) {
      uint2 w;
      w.x = pkbf(o0[4 * gg + 0] * a0 + mb[base + 4 * gg + 0] * a1,
                 o0[4 * gg + 1] * a0 + mb[base + 4 * gg + 1] * a1);
      w.y = pkbf(o0[4 * gg + 2] * a0 + mb[base + 4 * gg + 2] * a1,
                 o0[4 * gg + 3] * a0 + mb[base + 4 * gg + 3] * a1);
      *(uint2*)(ob + 8 * gg + 4 * hi) = w;
      w.x = pkbf(o1[4 * gg + 0] * a0 + mb[base + 16 + 4 * gg + 0] * a1,
                 o1[4 * gg + 1] * a0 + mb[base + 16 + 4 * gg + 1] * a1);
      w.y = pkbf(o1[4 * gg + 2] * a0 + mb[base + 16 + 4 * gg + 2] * a1,
                 o1[4 * gg + 3] * a0 + mb[base + 16 + 4 * gg + 3] * a1);
      *(uint2*)(ob + 32 + 8 * gg + 4 * hi) = w;
    }
  }
}

extern "C" void kernel_launch(void* const* d_in, const int* in_sizes, int n_in,
                              void* d_out, int out_size, void* d_ws, size_t ws_size,
                              hipStream_t stream)
{
  (void)in_sizes; (void)n_in; (void)out_size; (void)ws_size;
  const float* x      = (const float*)d_in[0];
  const float* w_qkv  = (const float*)d_in[1];
  const float* b_qkv  = (const float*)d_in[2];
  const float* w_proj = (const float*)d_in[3];
  const float* b_proj = (const float*)d_in[4];
  const float* q_g    = (const float*)d_in[5];
  const float* q_b    = (const float*)d_in[6];
  const float* k_g    = (const float*)d_in[7];
  const float* k_b    = (const float*)d_in[8];
  float* out = (float*)d_out;

  char* p = (char*)d_ws;
  unsigned short* x_bf  = (unsigned short*)p;  p += (size_t)4096 * 1024 * 2;
  unsigned short* wq_bf = (unsigned short*)p;  p += (size_t)3072 * 1024 * 2;
  unsigned short* wp_bf = (unsigned short*)p;  p += (size_t)1024 * 1024 * 2;
  unsigned short* qh    = (unsigned short*)p;  p += (size_t)32 * 2048 * 64 * 2;
  unsigned short* kh    = (unsigned short*)p;  p += (size_t)32 * 2048 * 64 * 2;
  unsigned short* vfr   = (unsigned short*)p;  p += (size_t)32 * 131072 * 2;
  unsigned short* ao    = (unsigned short*)p;  p += (size_t)4096 * 1024 * 2;

  k_cvt3<<<8192, 256, 0, stream>>>(x, w_qkv, w_proj, x_bf);

  k_gemm_qkv<<<dim3(24, 32), 256, 0, stream>>>(x_bf, wq_bf, b_qkv,
                                               q_g, q_b, k_g, k_b, qh, kh, vfr);
  k_attn<<<1024, 256, 0, stream>>>(qh, kh, vfr, ao);
  k_gemm<64, 128, 1, 4><<<dim3(8, 64), 256, 0, stream>>>(ao, wp_bf, b_proj, out, 4096, 1024, 1024);
}

// Round 16
// 137.768 us; speedup vs baseline: 1.1205x; 1.1189x over previous
//
#include <hip/hip_runtime.h>
#include <hip/hip_bf16.h>

// B=2, S=2048, D=1024, H=16, Hd=64
// cvt(fused x,wq,wp) -> QKV GEMM + fused LN/split/V-frag-major epilogue ->
// flash attention (swapped-QK, kv-split 2x, V-regs-before-K-staging vmcnt
// ordering, STAGE-first K dbuf) -> proj GEMM
// [r16 = exact revert to the r10 artifact: best measured state 137.87 us;
//  T15 double-pipeline (r15) regressed 59->74.7 us + 30 ms outlier dispatch]

typedef __attribute__((ext_vector_type(8)))  short bf16x8;   // 8 bf16 (4 VGPRs)
typedef __attribute__((ext_vector_type(4)))  float f32x4;
typedef __attribute__((ext_vector_type(16))) float f32x16;

__device__ __forceinline__ unsigned short f2bf(float f) {
  union { float f; unsigned u; } v; v.f = f;
  unsigned r = v.u + 0x7FFFu + ((v.u >> 16) & 1u);
  return (unsigned short)(r >> 16);
}

__device__ __forceinline__ unsigned pkbf(float a, float b) {
  unsigned r;
  asm("v_cvt_pk_bf16_f32 %0, %1, %2" : "=v"(r) : "v"(a), "v"(b));
  return r;
}

__device__ __forceinline__ void pl32swap(unsigned& x, unsigned& y) {
  asm("v_permlane32_swap_b32 %0, %1" : "+v"(x), "+v"(y));
}

// raw-rate exp2 (args bounded by defer-max; denormal flush-to-0 is fine here)
__device__ __forceinline__ float fexp2(float x) {
  float r; asm("v_exp_f32 %0, %1" : "=v"(r) : "v"(x)); return r;
}

__device__ __forceinline__ void gld_lds16(const void* g, void* l) {
  __builtin_amdgcn_global_load_lds(
      (const __attribute__((address_space(1))) void*)g,
      (__attribute__((address_space(3))) void*)l, 16, 0, 0);
}

// ---------------- fused fp32 -> bf16 convert (x, w_qkv, w_proj; outs contiguous) ----------------
__global__ __launch_bounds__(256) void k_cvt3(const float* __restrict__ x,
                                              const float* __restrict__ wq,
                                              const float* __restrict__ wp,
                                              unsigned short* __restrict__ d) {
  int i = blockIdx.x * 256 + threadIdx.x;       // 0 .. 2097151 float4 units
  const float* s;
  int off;
  if (i < 1048576)      { s = x;  off = i; }
  else if (i < 1835008) { s = wq; off = i - 1048576; }
  else                  { s = wp; off = i - 1835008; }
  float4 v = ((const float4*)s)[off];
  ushort4 o;
  o.x = f2bf(v.x); o.y = f2bf(v.y); o.z = f2bf(v.z); o.w = f2bf(v.w);
  ((ushort4*)d)[i] = o;
}

// ---------------- generic NT bf16 GEMM (proj) ----------------
template<int BM, int BN, int WM, int WN>
__global__ __launch_bounds__(256) void k_gemm(
    const unsigned short* __restrict__ A, const unsigned short* __restrict__ B,
    const float* __restrict__ bias, float* __restrict__ C, int M, int N, int K)
{
  constexpr int FM = BM / WM / 16;
  constexpr int FN = BN / WN / 16;
  __shared__ unsigned short lA[BM * 64];
  __shared__ unsigned short lB[BN * 64];
  int tid = threadIdx.x;
  int lane = tid & 63, wid = tid >> 6;
  int lg = lane >> 4, lo = lane & 15;
  int wm = wid / WN, wn = wid % WN;
  int m0 = blockIdx.y * BM, n0 = blockIdx.x * BN;

  f32x4 acc[FM][FN];
#pragma unroll
  for (int i = 0; i < FM; ++i)
#pragma unroll
    for (int j = 0; j < FN; ++j) acc[i][j] = (f32x4){0.f, 0.f, 0.f, 0.f};

  const int srow = tid >> 3, scol = (tid & 7) * 8;

  for (int kt = 0; kt < K; kt += 64) {
    __syncthreads();
#pragma unroll
    for (int i = 0; i < BM / 32; ++i)
      gld_lds16(A + (size_t)(m0 + srow + 32 * i) * K + kt + scol,
                &lA[(srow + 32 * i) * 64 + scol]);
#pragma unroll
    for (int i = 0; i < BN / 32; ++i)
      gld_lds16(B + (size_t)(n0 + srow + 32 * i) * K + kt + scol,
                &lB[(srow + 32 * i) * 64 + scol]);
    __syncthreads();

#pragma unroll
    for (int ks = 0; ks < 2; ++ks) {
      bf16x8 af[FM], bfr[FN];
#pragma unroll
      for (int i = 0; i < FM; ++i)
        af[i] = *(const bf16x8*)&lA[(wm * (BM / WM) + i * 16 + lo) * 64 + ks * 32 + lg * 8];
#pragma unroll
      for (int j = 0; j < FN; ++j)
        bfr[j] = *(const bf16x8*)&lB[(wn * (BN / WN) + j * 16 + lo) * 64 + ks * 32 + lg * 8];
      __builtin_amdgcn_s_setprio(1);
#pragma unroll
      for (int i = 0; i < FM; ++i)
#pragma unroll
        for (int j = 0; j < FN; ++j)
          acc[i][j] = __builtin_amdgcn_mfma_f32_16x16x32_bf16(af[i], bfr[j], acc[i][j], 0, 0, 0);
      __builtin_amdgcn_s_setprio(0);
    }
  }

#pragma unroll
  for (int j = 0; j < FN; ++j) {
    int col = n0 + wn * (BN / WN) + j * 16 + lo;
    float bb = bias[col];
#pragma unroll
    for (int i = 0; i < FM; ++i)
#pragma unroll
      for (int r = 0; r < 4; ++r) {
        int row = m0 + wm * (BM / WM) + i * 16 + lg * 4 + r;
        C[(size_t)row * N + col] = acc[i][j][r] + bb;
      }
  }
}

// ---------------- QKV GEMM with fused LN + split + V frag-major ----------------
__global__ __launch_bounds__(256) void k_gemm_qkv(
    const unsigned short* __restrict__ A,   // x_bf [4096][1024]
    const unsigned short* __restrict__ B,   // wq_bf [3072][1024]
    const float* __restrict__ bias,         // [3072]
    const float* __restrict__ qg, const float* __restrict__ qb,
    const float* __restrict__ kg, const float* __restrict__ kb,
    unsigned short* __restrict__ qh,        // [32][2048][64]
    unsigned short* __restrict__ kh,        // [32][2048][64]
    unsigned short* __restrict__ vf)        // [32][131072] frag-major
{
  __shared__ unsigned short lA[128 * 64];
  __shared__ unsigned short lB[128 * 64];
  int tid = threadIdx.x;
  int lane = tid & 63, wid = tid >> 6;
  int lg = lane >> 4, lo = lane & 15;
  int wm = wid >> 1, wn = wid & 1;
  int m0 = blockIdx.y * 128, n0 = blockIdx.x * 128;
  const int K = 1024;

  f32x4 acc[4][4];
#pragma unroll
  for (int i = 0; i < 4; ++i)
#pragma unroll
    for (int j = 0; j < 4; ++j) acc[i][j] = (f32x4){0.f, 0.f, 0.f, 0.f};

  const int srow = tid >> 3, scol = (tid & 7) * 8;

  for (int kt = 0; kt < K; kt += 64) {
    __syncthreads();
#pragma unroll
    for (int i = 0; i < 4; ++i)
      gld_lds16(A + (size_t)(m0 + srow + 32 * i) * K + kt + scol,
                &lA[(srow + 32 * i) * 64 + scol]);
#pragma unroll
    for (int i = 0; i < 4; ++i)
      gld_lds16(B + (size_t)(n0 + srow + 32 * i) * K + kt + scol,
                &lB[(srow + 32 * i) * 64 + scol]);
    __syncthreads();

#pragma unroll
    for (int ks = 0; ks < 2; ++ks) {
      bf16x8 af[4], bfr[4];
#pragma unroll
      for (int i = 0; i < 4; ++i)
        af[i] = *(const bf16x8*)&lA[(wm * 64 + i * 16 + lo) * 64 + ks * 32 + lg * 8];
#pragma unroll
      for (int j = 0; j < 4; ++j)
        bfr[j] = *(const bf16x8*)&lB[(wn * 64 + j * 16 + lo) * 64 + ks * 32 + lg * 8];
      __builtin_amdgcn_s_setprio(1);
#pragma unroll
      for (int i = 0; i < 4; ++i)
#pragma unroll
        for (int j = 0; j < 4; ++j)
          acc[i][j] = __builtin_amdgcn_mfma_f32_16x16x32_bf16(af[i], bfr[j], acc[i][j], 0, 0, 0);
      __builtin_amdgcn_s_setprio(0);
    }
  }

  // ---- fused epilogue ----
  int m0b = m0 & 2047;
  int bb_ = m0 >> 11;
  int hcol = (n0 + wn * 64) >> 6;      // 0..15 q, 16..31 k, 32..47 v
  float bias4[4];
#pragma unroll
  for (int j = 0; j < 4; ++j) bias4[j] = bias[n0 + wn * 64 + j * 16 + lo];

  if (hcol >= 32) {
    int bh = bb_ * 16 + (hcol - 32);
    int T = m0b >> 7;
    int hi_ = lg >> 1;
    int j8b = (lg & 1) * 4;
    unsigned short* vbase = vf + (size_t)bh * 131072 + T * 8192 + hi_ * 256 + j8b;
#pragma unroll
    for (int i = 0; i < 4; ++i) {
      int ss = wm * 4 + i;
#pragma unroll
      for (int j = 0; j < 4; ++j) {
        int dh = j >> 1, dp = (j & 1) * 16 + lo;
        uint2 w;
        w.x = pkbf(acc[i][j][0] + bias4[j], acc[i][j][1] + bias4[j]);
        w.y = pkbf(acc[i][j][2] + bias4[j], acc[i][j][3] + bias4[j]);
        *(uint2*)(vbase + ss * 1024 + dh * 512 + dp * 8) = w;
      }
    }
  } else {
    bool isq = hcol < 16;
    int bh = bb_ * 16 + (isq ? hcol : hcol - 16);
    const float* g = isq ? qg : kg;
    const float* bt = isq ? qb : kb;
    float osc = isq ? 0.18033688f : 1.0f;   // 0.125 * log2(e) folded into q
    float g4[4], t4[4];
#pragma unroll
    for (int j = 0; j < 4; ++j) {
      g4[j] = g[j * 16 + lo] * osc;
      t4[j] = bt[j * 16 + lo] * osc;
    }
    unsigned short* dst = (isq ? qh : kh) + (size_t)bh * 131072;
#pragma unroll
    for (int i = 0; i < 4; ++i) {
#pragma unroll
      for (int r = 0; r < 4; ++r) {
        float v0 = acc[i][0][r] + bias4[0];
        float v1 = acc[i][1][r] + bias4[1];
        float v2 = acc[i][2][r] + bias4[2];
        float v3 = acc[i][3][r] + bias4[3];
        float sm = (v0 + v1) + (v2 + v3);
        sm += __shfl_xor(sm, 1, 64); sm += __shfl_xor(sm, 2, 64);
        sm += __shfl_xor(sm, 4, 64); sm += __shfl_xor(sm, 8, 64);
        float mu = sm * (1.0f / 64.0f);
        float d0 = v0 - mu, d1 = v1 - mu, d2 = v2 - mu, d3 = v3 - mu;
        float vv = (d0 * d0 + d1 * d1) + (d2 * d2 + d3 * d3);
        vv += __shfl_xor(vv, 1, 64); vv += __shfl_xor(vv, 2, 64);
        vv += __shfl_xor(vv, 4, 64); vv += __shfl_xor(vv, 8, 64);
        float rs = rsqrtf(vv * (1.0f / 64.0f) + 1e-5f);
        int s = m0b + wm * 64 + i * 16 + lg * 4 + r;
        unsigned short* row = dst + (size_t)s * 64 + lo;
        row[0]  = f2bf(fmaf(d0 * rs, g4[0], t4[0]));
        row[16] = f2bf(fmaf(d1 * rs, g4[1], t4[1]));
        row[32] = f2bf(fmaf(d2 * rs, g4[2], t4[2]));
        row[48] = f2bf(fmaf(d3 * rs, g4[3], t4[3]));
      }
    }
  }
}

// ---------------- flash attention v10 (best measured: ~59 us) ----------------
__global__ __launch_bounds__(256, 3) void k_attn(
    const unsigned short* __restrict__ Q,   // [BH][S][64] (pre-scaled)
    const unsigned short* __restrict__ K,   // [BH][S][64]
    const unsigned short* __restrict__ VF,  // [BH][131072] frag-major
    unsigned short* __restrict__ O)         // [B*S][1024] bf16
{
  __shared__ char lK[2][16384];   // 32 KB: [buf][g*8192 + row*128 + col]

  int tid = threadIdx.x;
  int wid = tid >> 6, lane = tid & 63;
  int l31 = lane & 31, hi = lane >> 5;
  int qc = wid >> 1, g = wid & 1;

  int id = blockIdx.x;                       // 1024 blocks, XCD-bijective
  int nid = (id & 7) * 128 + (id >> 3);
  int bh = nid >> 5;
  int q0 = (nid & 31) << 6;                  // 64 q-rows per block
  int q = q0 + qc * 32 + l31;

  const unsigned short* qp = Q + ((size_t)bh * 2048 + q) * 64 + hi * 8;
  bf16x8 qf[4];
#pragma unroll
  for (int s = 0; s < 4; ++s) qf[s] = *(const bf16x8*)(qp + 16 * s);

  const char* kbytes = (const char*)(K + (size_t)bh * 131072);
  const unsigned short* vfb = VF + (size_t)bh * 131072 + lane * 8;

  f32x16 z16;                                // persistent zero frag
#pragma unroll
  for (int i = 0; i < 16; ++i) z16[i] = 0.f;
  float m = -1e30f, lsum = 0.0f;
  f32x16 o0 = z16, o1 = z16;

  // prologue: stage pair 0 (tiles 0,1) into buf 0
#pragma unroll
  for (int ii = 0; ii < 4; ++ii) {
    int b = ii * 4096 + tid * 16;
    int sb = b ^ (((b >> 7) & 7) << 4);      // involution (bits 4-6)
    gld_lds16(kbytes + sb, &lK[0][b]);
  }
  __syncthreads();

  int pb = 0;
  for (int i = 0; i < 16; ++i) {
    const char* bK = &lK[pb][g * 8192];
    const unsigned short* vt = vfb + (size_t)(2 * i + g) * 4096;

    // (1) current-tile V -> regs FIRST (oldest in vmcnt queue)
    bf16x8 vv[8];
#pragma unroll
    for (int s = 0; s < 4; ++s) {
      vv[2 * s]     = *(const bf16x8*)(vt + s * 1024);
      vv[2 * s + 1] = *(const bf16x8*)(vt + s * 1024 + 512);
    }
    __builtin_amdgcn_sched_barrier(0);       // pin: V loads precede gld_lds

    // (2) next pair's K staging (stays in flight until the barrier)
    if (i < 15) {
#pragma unroll
      for (int ii = 0; ii < 4; ++ii) {
        int b = ii * 4096 + tid * 16;
        int sb = b ^ (((b >> 7) & 7) << 4);
        gld_lds16(kbytes + (size_t)(i + 1) * 16384 + sb, &lK[pb ^ 1][b]);
      }
    }

    // ---- QK^T: 2 fragments of 32 kv; zero-frag init ----
    f32x16 sc[2];
    __builtin_amdgcn_s_setprio(1);
#pragma unroll
    for (int c = 0; c < 2; ++c) {
      int row = c * 32 + l31;
      int rx = (row * 128) ^ ((row & 7) << 4);
      bf16x8 kf = *(const bf16x8*)(bK + (rx ^ (hi * 16)));
      sc[c] = __builtin_amdgcn_mfma_f32_32x32x16_bf16(kf, qf[0], z16, 0, 0, 0);
#pragma unroll
      for (int s = 1; s < 4; ++s) {
        kf = *(const bf16x8*)(bK + (rx ^ ((2 * s + hi) * 16)));
        sc[c] = __builtin_amdgcn_mfma_f32_32x32x16_bf16(kf, qf[s], sc[c], 0, 0, 0);
      }
    }
    __builtin_amdgcn_s_setprio(0);

    // ---- max tree (max3-fusable) over 32 values ----
    float r[8];
#pragma unroll
    for (int i2 = 0; i2 < 8; ++i2)
      r[i2] = fmaxf(fmaxf(sc[0][i2], sc[0][i2 + 8]),
                    fmaxf(sc[1][i2], sc[1][i2 + 8]));
    float pm = fmaxf(fmaxf(fmaxf(r[0], r[1]), fmaxf(r[2], r[3])),
                     fmaxf(fmaxf(r[4], r[5]), fmaxf(r[6], r[7])));
    pm = fmaxf(pm, __shfl_xor(pm, 32, 64));

    if (!__all(pm - m <= 8.0f)) {            // defer-max
      float mn = fmaxf(m, pm);
      float fac = fexp2(m - mn);
      m = mn;
      lsum *= fac;
#pragma unroll
      for (int i2 = 0; i2 < 16; ++i2) { o0[i2] *= fac; o1[i2] *= fac; }
    }

    // ---- raw-rate exp2 + tree sum ----
#pragma unroll
    for (int c = 0; c < 2; ++c)
#pragma unroll
      for (int i2 = 0; i2 < 16; ++i2) sc[c][i2] = fexp2(sc[c][i2] - m);
    float ts[16];
#pragma unroll
    for (int i2 = 0; i2 < 16; ++i2) ts[i2] = sc[0][i2] + sc[1][i2];
#pragma unroll
    for (int d = 8; d; d >>= 1)
#pragma unroll
      for (int i2 = 0; i2 < d; ++i2) ts[i2] += ts[i2 + d];
    lsum += ts[0] + __shfl_xor(ts[0], 32, 64);

    // ---- PV: 4 s-steps of 16 kv; V already in regs ----
#pragma unroll
    for (int s = 0; s < 4; ++s) {
      const f32x16& sf = sc[s >> 1];
      const int rb = (s & 1) * 8;
      unsigned d0 = pkbf(sf[rb + 0], sf[rb + 1]);
      unsigned d1 = pkbf(sf[rb + 2], sf[rb + 3]);
      unsigned d2 = pkbf(sf[rb + 4], sf[rb + 5]);
      unsigned d3 = pkbf(sf[rb + 6], sf[rb + 7]);
      pl32swap(d0, d2);
      pl32swap(d1, d3);
      union { unsigned u[4]; bf16x8 v; } pu;
      pu.u[0] = d0; pu.u[1] = d1; pu.u[2] = d2; pu.u[3] = d3;
      __builtin_amdgcn_s_setprio(1);
      o0 = __builtin_amdgcn_mfma_f32_32x32x16_bf16(vv[2 * s],     pu.v, o0, 0, 0, 0);
      o1 = __builtin_amdgcn_mfma_f32_32x32x16_bf16(vv[2 * s + 1], pu.v, o1, 0, 0, 0);
      __builtin_amdgcn_s_setprio(0);
    }

    __syncthreads();   // K staging had the whole iteration in flight
    pb ^= 1;
  }

  // ---- kv-group merge via LDS (reuse lK) ----
  float* mb = (float*)&lK[0][0];
  int base = (qc * 64 + lane) * 34;
  if (g) {
#pragma unroll
    for (int i2 = 0; i2 < 16; ++i2) { mb[base + i2] = o0[i2]; mb[base + 16 + i2] = o1[i2]; }
    mb[base + 32] = m; mb[base + 33] = lsum;
  }
  __syncthreads();
  if (!g) {
    float m1 = mb[base + 32], l1 = mb[base + 33];
    float mn = fmaxf(m, m1);
    float f0 = fexp2(m - mn), f1 = fexp2(m1 - mn);
    float linv = 1.0f / (lsum * f0 + l1 * f1);
    float a0 = f0 * linv, a1 = f1 * linv;
    int b = bh >> 4, h = bh & 15;
    unsigned short* ob = O + ((size_t)(b * 2048 + q)) * 1024 + h * 64;
#pragma unroll
    for (int gg = 0; gg < 4; ++gg) {
      uint2 w;
      w.x = pkbf(o0[4 * gg + 0] * a0 + mb[base + 4 * gg + 0] * a1,
                 o0[4 * gg + 1] * a0 + mb[base + 4 * gg + 1] * a1);
      w.y = pkbf(o0[4 * gg + 2] * a0 + mb[base + 4 * gg + 2] * a1,
                 o0[4 * gg + 3] * a0 + mb[base + 4 * gg + 3] * a1);
      *(uint2*)(ob + 8 * gg + 4 * hi) = w;
      w.x = pkbf(o1[4 * gg + 0] * a0 + mb[base + 16 + 4 * gg + 0] * a1,
                 o1[4 * gg + 1] * a0 + mb[base + 16 + 4 * gg + 1] * a1);
      w.y = pkbf(o1[4 * gg + 2] * a0 + mb[base + 16 + 4 * gg + 2] * a1,
                 o1[4 * gg + 3] * a0 + mb[base + 16 + 4 * gg + 3] * a1);
      *(uint2*)(ob + 32 + 8 * gg + 4 * hi) = w;
    }
  }
}

extern "C" void kernel_launch(void* const* d_in, const int* in_sizes, int n_in,
                              void* d_out, int out_size, void* d_ws, size_t ws_size,
                              hipStream_t stream)
{
  (void)in_sizes; (void)n_in; (void)out_size; (void)ws_size;
  const float* x      = (const float*)d_in[0];
  const float* w_qkv  = (const float*)d_in[1];
  const float* b_qkv  = (const float*)d_in[2];
  const float* w_proj = (const float*)d_in[3];
  const float* b_proj = (const float*)d_in[4];
  const float* q_g    = (const float*)d_in[5];
  const float* q_b    = (const float*)d_in[6];
  const float* k_g    = (const float*)d_in[7];
  const float* k_b    = (const float*)d_in[8];
  float* out = (float*)d_out;

  char* p = (char*)d_ws;
  unsigned short* x_bf  = (unsigned short*)p;  p += (size_t)4096 * 1024 * 2;
  unsigned short* wq_bf = (unsigned short*)p;  p += (size_t)3072 * 1024 * 2;
  unsigned short* wp_bf = (unsigned short*)p;  p += (size_t)1024 * 1024 * 2;
  unsigned short* qh    = (unsigned short*)p;  p += (size_t)32 * 2048 * 64 * 2;
  unsigned short* kh    = (unsigned short*)p;  p += (size_t)32 * 2048 * 64 * 2;
  unsigned short* vfr   = (unsigned short*)p;  p += (size_t)32 * 131072 * 2;
  unsigned short* ao    = (unsigned short*)p;  p += (size_t)4096 * 1024 * 2;

  k_cvt3<<<8192, 256, 0, stream>>>(x, w_qkv, w_proj, x_bf);   // outs contiguous

  k_gemm_qkv<<<dim3(24, 32), 256, 0, stream>>>(x_bf, wq_bf, b_qkv,
                                               q_g, q_b, k_g, k_b, qh, kh, vfr);
  k_attn<<<1024, 256, 0, stream>>>(qh, kh, vfr, ao);
  k_gemm<64, 128, 1, 4><<<dim3(8, 64), 256, 0, stream>>>(ao, wp_bf, b_proj, out, 4096, 1024, 1024);
}

// Round 17
// 126.091 us; speedup vs baseline: 1.2242x; 1.0926x over previous
//
#include <hip/hip_runtime.h>
#include <hip/hip_bf16.h>

// B=2, S=2048, D=1024, H=16, Hd=64
// cvt(fused x,wq,wp) -> QKV GEMM (2-phase dbuf BK=32) + fused LN/split/V-frag
// epilogue -> flash attention (r10 v10, untouched) -> proj GEMM (2-phase dbuf)

typedef __attribute__((ext_vector_type(8)))  short bf16x8;   // 8 bf16 (4 VGPRs)
typedef __attribute__((ext_vector_type(4)))  float f32x4;
typedef __attribute__((ext_vector_type(16))) float f32x16;

__device__ __forceinline__ unsigned short f2bf(float f) {
  union { float f; unsigned u; } v; v.f = f;
  unsigned r = v.u + 0x7FFFu + ((v.u >> 16) & 1u);
  return (unsigned short)(r >> 16);
}

__device__ __forceinline__ unsigned pkbf(float a, float b) {
  unsigned r;
  asm("v_cvt_pk_bf16_f32 %0, %1, %2" : "=v"(r) : "v"(a), "v"(b));
  return r;
}

__device__ __forceinline__ void pl32swap(unsigned& x, unsigned& y) {
  asm("v_permlane32_swap_b32 %0, %1" : "+v"(x), "+v"(y));
}

// raw-rate exp2 (args bounded by defer-max; denormal flush-to-0 is fine here)
__device__ __forceinline__ float fexp2(float x) {
  float r; asm("v_exp_f32 %0, %1" : "=v"(r) : "v"(x)); return r;
}

__device__ __forceinline__ void gld_lds16(const void* g, void* l) {
  __builtin_amdgcn_global_load_lds(
      (const __attribute__((address_space(1))) void*)g,
      (__attribute__((address_space(3))) void*)l, 16, 0, 0);
}

// ---------------- fused fp32 -> bf16 convert (x, w_qkv, w_proj; outs contiguous) ----------------
__global__ __launch_bounds__(256) void k_cvt3(const float* __restrict__ x,
                                              const float* __restrict__ wq,
                                              const float* __restrict__ wp,
                                              unsigned short* __restrict__ d) {
  int i = blockIdx.x * 256 + threadIdx.x;       // 0 .. 2097151 float4 units
  const float* s;
  int off;
  if (i < 1048576)      { s = x;  off = i; }
  else if (i < 1835008) { s = wq; off = i - 1048576; }
  else                  { s = wp; off = i - 1835008; }
  float4 v = ((const float4*)s)[off];
  ushort4 o;
  o.x = f2bf(v.x); o.y = f2bf(v.y); o.z = f2bf(v.z); o.w = f2bf(v.w);
  ((ushort4*)d)[i] = o;
}

// ---------------- generic NT bf16 GEMM (proj): 2-phase dbuf, BK=32 ----------------
// STAGE-first: issue next K-step's gld_lds into buf^1, compute from buf,
// ONE barrier per iteration (vmcnt drain covered by the MFMA phase).
template<int BM, int BN, int WM, int WN>
__global__ __launch_bounds__(256) void k_gemm(
    const unsigned short* __restrict__ A, const unsigned short* __restrict__ B,
    const float* __restrict__ bias, float* __restrict__ C, int M, int N, int K)
{
  constexpr int FM = BM / WM / 16;
  constexpr int FN = BN / WN / 16;
  __shared__ unsigned short lA[2][BM * 32];
  __shared__ unsigned short lB[2][BN * 32];
  int tid = threadIdx.x;
  int lane = tid & 63, wid = tid >> 6;
  int lg = lane >> 4, lo = lane & 15;
  int wm = wid / WN, wn = wid % WN;
  int m0 = blockIdx.y * BM, n0 = blockIdx.x * BN;

  f32x4 acc[FM][FN];
#pragma unroll
  for (int i = 0; i < FM; ++i)
#pragma unroll
    for (int j = 0; j < FN; ++j) acc[i][j] = (f32x4){0.f, 0.f, 0.f, 0.f};

  // staging coords: 64 rows x 4 chunks of 16B per 256 threads per pass
  const int srow = tid >> 2, scol = (tid & 3) * 8;

  // prologue: stage kt=0 into buf 0
#pragma unroll
  for (int i = 0; i < BM / 64; ++i)
    gld_lds16(A + (size_t)(m0 + srow + 64 * i) * K + scol,
              &lA[0][(srow + 64 * i) * 32 + scol]);
#pragma unroll
  for (int i = 0; i < BN / 64; ++i)
    gld_lds16(B + (size_t)(n0 + srow + 64 * i) * K + scol,
              &lB[0][(srow + 64 * i) * 32 + scol]);
  __syncthreads();

  const int NT = K / 32;
  int pb = 0;
  for (int t = 0; t < NT; ++t) {
    // phase 1: issue next K-step's staging FIRST (hides under MFMA)
    if (t < NT - 1) {
      int kt = (t + 1) * 32;
#pragma unroll
      for (int i = 0; i < BM / 64; ++i)
        gld_lds16(A + (size_t)(m0 + srow + 64 * i) * K + kt + scol,
                  &lA[pb ^ 1][(srow + 64 * i) * 32 + scol]);
#pragma unroll
      for (int i = 0; i < BN / 64; ++i)
        gld_lds16(B + (size_t)(n0 + srow + 64 * i) * K + kt + scol,
                  &lB[pb ^ 1][(srow + 64 * i) * 32 + scol]);
    }

    // phase 2: compute current K-step (BK=32 = one MFMA k-step)
    bf16x8 af[FM], bfr[FN];
#pragma unroll
    for (int i = 0; i < FM; ++i)
      af[i] = *(const bf16x8*)&lA[pb][(wm * (BM / WM) + i * 16 + lo) * 32 + lg * 8];
#pragma unroll
    for (int j = 0; j < FN; ++j)
      bfr[j] = *(const bf16x8*)&lB[pb][(wn * (BN / WN) + j * 16 + lo) * 32 + lg * 8];
    __builtin_amdgcn_s_setprio(1);
#pragma unroll
    for (int i = 0; i < FM; ++i)
#pragma unroll
      for (int j = 0; j < FN; ++j)
        acc[i][j] = __builtin_amdgcn_mfma_f32_16x16x32_bf16(af[i], bfr[j], acc[i][j], 0, 0, 0);
    __builtin_amdgcn_s_setprio(0);

    __syncthreads();   // staging had the whole MFMA phase in flight
    pb ^= 1;
  }

#pragma unroll
  for (int j = 0; j < FN; ++j) {
    int col = n0 + wn * (BN / WN) + j * 16 + lo;
    float bb = bias[col];
#pragma unroll
    for (int i = 0; i < FM; ++i)
#pragma unroll
      for (int r = 0; r < 4; ++r) {
        int row = m0 + wm * (BM / WM) + i * 16 + lg * 4 + r;
        C[(size_t)row * N + col] = acc[i][j][r] + bb;
      }
  }
}

// ---------------- QKV GEMM: 2-phase dbuf BK=32 + fused LN/split/V frag-major ----------------
__global__ __launch_bounds__(256) void k_gemm_qkv(
    const unsigned short* __restrict__ A,   // x_bf [4096][1024]
    const unsigned short* __restrict__ B,   // wq_bf [3072][1024]
    const float* __restrict__ bias,         // [3072]
    const float* __restrict__ qg, const float* __restrict__ qb,
    const float* __restrict__ kg, const float* __restrict__ kb,
    unsigned short* __restrict__ qh,        // [32][2048][64]
    unsigned short* __restrict__ kh,        // [32][2048][64]
    unsigned short* __restrict__ vf)        // [32][131072] frag-major
{
  __shared__ unsigned short lA[2][128 * 32];
  __shared__ unsigned short lB[2][128 * 32];
  int tid = threadIdx.x;
  int lane = tid & 63, wid = tid >> 6;
  int lg = lane >> 4, lo = lane & 15;
  int wm = wid >> 1, wn = wid & 1;
  int m0 = blockIdx.y * 128, n0 = blockIdx.x * 128;
  const int K = 1024;

  f32x4 acc[4][4];
#pragma unroll
  for (int i = 0; i < 4; ++i)
#pragma unroll
    for (int j = 0; j < 4; ++j) acc[i][j] = (f32x4){0.f, 0.f, 0.f, 0.f};

  const int srow = tid >> 2, scol = (tid & 3) * 8;

  // prologue: stage kt=0 into buf 0
#pragma unroll
  for (int i = 0; i < 2; ++i) {
    gld_lds16(A + (size_t)(m0 + srow + 64 * i) * K + scol,
              &lA[0][(srow + 64 * i) * 32 + scol]);
    gld_lds16(B + (size_t)(n0 + srow + 64 * i) * K + scol,
              &lB[0][(srow + 64 * i) * 32 + scol]);
  }
  __syncthreads();

  int pb = 0;
  for (int t = 0; t < 32; ++t) {
    if (t < 31) {
      int kt = (t + 1) * 32;
#pragma unroll
      for (int i = 0; i < 2; ++i) {
        gld_lds16(A + (size_t)(m0 + srow + 64 * i) * K + kt + scol,
                  &lA[pb ^ 1][(srow + 64 * i) * 32 + scol]);
        gld_lds16(B + (size_t)(n0 + srow + 64 * i) * K + kt + scol,
                  &lB[pb ^ 1][(srow + 64 * i) * 32 + scol]);
      }
    }

    bf16x8 af[4], bfr[4];
#pragma unroll
    for (int i = 0; i < 4; ++i)
      af[i] = *(const bf16x8*)&lA[pb][(wm * 64 + i * 16 + lo) * 32 + lg * 8];
#pragma unroll
    for (int j = 0; j < 4; ++j)
      bfr[j] = *(const bf16x8*)&lB[pb][(wn * 64 + j * 16 + lo) * 32 + lg * 8];
    __builtin_amdgcn_s_setprio(1);
#pragma unroll
    for (int i = 0; i < 4; ++i)
#pragma unroll
      for (int j = 0; j < 4; ++j)
        acc[i][j] = __builtin_amdgcn_mfma_f32_16x16x32_bf16(af[i], bfr[j], acc[i][j], 0, 0, 0);
    __builtin_amdgcn_s_setprio(0);

    __syncthreads();
    pb ^= 1;
  }

  // ---- fused epilogue (unchanged, verified r9/r10) ----
  int m0b = m0 & 2047;
  int bb_ = m0 >> 11;
  int hcol = (n0 + wn * 64) >> 6;      // 0..15 q, 16..31 k, 32..47 v
  float bias4[4];
#pragma unroll
  for (int j = 0; j < 4; ++j) bias4[j] = bias[n0 + wn * 64 + j * 16 + lo];

  if (hcol >= 32) {
    int bh = bb_ * 16 + (hcol - 32);
    int T = m0b >> 7;
    int hi_ = lg >> 1;
    int j8b = (lg & 1) * 4;
    unsigned short* vbase = vf + (size_t)bh * 131072 + T * 8192 + hi_ * 256 + j8b;
#pragma unroll
    for (int i = 0; i < 4; ++i) {
      int ss = wm * 4 + i;
#pragma unroll
      for (int j = 0; j < 4; ++j) {
        int dh = j >> 1, dp = (j & 1) * 16 + lo;
        uint2 w;
        w.x = pkbf(acc[i][j][0] + bias4[j], acc[i][j][1] + bias4[j]);
        w.y = pkbf(acc[i][j][2] + bias4[j], acc[i][j][3] + bias4[j]);
        *(uint2*)(vbase + ss * 1024 + dh * 512 + dp * 8) = w;
      }
    }
  } else {
    bool isq = hcol < 16;
    int bh = bb_ * 16 + (isq ? hcol : hcol - 16);
    const float* g = isq ? qg : kg;
    const float* bt = isq ? qb : kb;
    float osc = isq ? 0.18033688f : 1.0f;   // 0.125 * log2(e) folded into q
    float g4[4], t4[4];
#pragma unroll
    for (int j = 0; j < 4; ++j) {
      g4[j] = g[j * 16 + lo] * osc;
      t4[j] = bt[j * 16 + lo] * osc;
    }
    unsigned short* dst = (isq ? qh : kh) + (size_t)bh * 131072;
#pragma unroll
    for (int i = 0; i < 4; ++i) {
#pragma unroll
      for (int r = 0; r < 4; ++r) {
        float v0 = acc[i][0][r] + bias4[0];
        float v1 = acc[i][1][r] + bias4[1];
        float v2 = acc[i][2][r] + bias4[2];
        float v3 = acc[i][3][r] + bias4[3];
        float sm = (v0 + v1) + (v2 + v3);
        sm += __shfl_xor(sm, 1, 64); sm += __shfl_xor(sm, 2, 64);
        sm += __shfl_xor(sm, 4, 64); sm += __shfl_xor(sm, 8, 64);
        float mu = sm * (1.0f / 64.0f);
        float d0 = v0 - mu, d1 = v1 - mu, d2 = v2 - mu, d3 = v3 - mu;
        float vv = (d0 * d0 + d1 * d1) + (d2 * d2 + d3 * d3);
        vv += __shfl_xor(vv, 1, 64); vv += __shfl_xor(vv, 2, 64);
        vv += __shfl_xor(vv, 4, 64); vv += __shfl_xor(vv, 8, 64);
        float rs = rsqrtf(vv * (1.0f / 64.0f) + 1e-5f);
        int s = m0b + wm * 64 + i * 16 + lg * 4 + r;
        unsigned short* row = dst + (size_t)s * 64 + lo;
        row[0]  = f2bf(fmaf(d0 * rs, g4[0], t4[0]));
        row[16] = f2bf(fmaf(d1 * rs, g4[1], t4[1]));
        row[32] = f2bf(fmaf(d2 * rs, g4[2], t4[2]));
        row[48] = f2bf(fmaf(d3 * rs, g4[3], t4[3]));
      }
    }
  }
}

// ---------------- flash attention v10 (best measured: ~59 us; untouched) ----------------
__global__ __launch_bounds__(256, 3) void k_attn(
    const unsigned short* __restrict__ Q,   // [BH][S][64] (pre-scaled)
    const unsigned short* __restrict__ K,   // [BH][S][64]
    const unsigned short* __restrict__ VF,  // [BH][131072] frag-major
    unsigned short* __restrict__ O)         // [B*S][1024] bf16
{
  __shared__ char lK[2][16384];   // 32 KB: [buf][g*8192 + row*128 + col]

  int tid = threadIdx.x;
  int wid = tid >> 6, lane = tid & 63;
  int l31 = lane & 31, hi = lane >> 5;
  int qc = wid >> 1, g = wid & 1;

  int id = blockIdx.x;                       // 1024 blocks, XCD-bijective
  int nid = (id & 7) * 128 + (id >> 3);
  int bh = nid >> 5;
  int q0 = (nid & 31) << 6;                  // 64 q-rows per block
  int q = q0 + qc * 32 + l31;

  const unsigned short* qp = Q + ((size_t)bh * 2048 + q) * 64 + hi * 8;
  bf16x8 qf[4];
#pragma unroll
  for (int s = 0; s < 4; ++s) qf[s] = *(const bf16x8*)(qp + 16 * s);

  const char* kbytes = (const char*)(K + (size_t)bh * 131072);
  const unsigned short* vfb = VF + (size_t)bh * 131072 + lane * 8;

  f32x16 z16;                                // persistent zero frag
#pragma unroll
  for (int i = 0; i < 16; ++i) z16[i] = 0.f;
  float m = -1e30f, lsum = 0.0f;
  f32x16 o0 = z16, o1 = z16;

  // prologue: stage pair 0 (tiles 0,1) into buf 0
#pragma unroll
  for (int ii = 0; ii < 4; ++ii) {
    int b = ii * 4096 + tid * 16;
    int sb = b ^ (((b >> 7) & 7) << 4);      // involution (bits 4-6)
    gld_lds16(kbytes + sb, &lK[0][b]);
  }
  __syncthreads();

  int pb = 0;
  for (int i = 0; i < 16; ++i) {
    const char* bK = &lK[pb][g * 8192];
    const unsigned short* vt = vfb + (size_t)(2 * i + g) * 4096;

    // (1) current-tile V -> regs FIRST (oldest in vmcnt queue)
    bf16x8 vv[8];
#pragma unroll
    for (int s = 0; s < 4; ++s) {
      vv[2 * s]     = *(const bf16x8*)(vt + s * 1024);
      vv[2 * s + 1] = *(const bf16x8*)(vt + s * 1024 + 512);
    }
    __builtin_amdgcn_sched_barrier(0);       // pin: V loads precede gld_lds

    // (2) next pair's K staging (stays in flight until the barrier)
    if (i < 15) {
#pragma unroll
      for (int ii = 0; ii < 4; ++ii) {
        int b = ii * 4096 + tid * 16;
        int sb = b ^ (((b >> 7) & 7) << 4);
        gld_lds16(kbytes + (size_t)(i + 1) * 16384 + sb, &lK[pb ^ 1][b]);
      }
    }

    // ---- QK^T: 2 fragments of 32 kv; zero-frag init ----
    f32x16 sc[2];
    __builtin_amdgcn_s_setprio(1);
#pragma unroll
    for (int c = 0; c < 2; ++c) {
      int row = c * 32 + l31;
      int rx = (row * 128) ^ ((row & 7) << 4);
      bf16x8 kf = *(const bf16x8*)(bK + (rx ^ (hi * 16)));
      sc[c] = __builtin_amdgcn_mfma_f32_32x32x16_bf16(kf, qf[0], z16, 0, 0, 0);
#pragma unroll
      for (int s = 1; s < 4; ++s) {
        kf = *(const bf16x8*)(bK + (rx ^ ((2 * s + hi) * 16)));
        sc[c] = __builtin_amdgcn_mfma_f32_32x32x16_bf16(kf, qf[s], sc[c], 0, 0, 0);
      }
    }
    __builtin_amdgcn_s_setprio(0);

    // ---- max tree (max3-fusable) over 32 values ----
    float r[8];
#pragma unroll
    for (int i2 = 0; i2 < 8; ++i2)
      r[i2] = fmaxf(fmaxf(sc[0][i2], sc[0][i2 + 8]),
                    fmaxf(sc[1][i2], sc[1][i2 + 8]));
    float pm = fmaxf(fmaxf(fmaxf(r[0], r[1]), fmaxf(r[2], r[3])),
                     fmaxf(fmaxf(r[4], r[5]), fmaxf(r[6], r[7])));
    pm = fmaxf(pm, __shfl_xor(pm, 32, 64));

    if (!__all(pm - m <= 8.0f)) {            // defer-max
      float mn = fmaxf(m, pm);
      float fac = fexp2(m - mn);
      m = mn;
      lsum *= fac;
#pragma unroll
      for (int i2 = 0; i2 < 16; ++i2) { o0[i2] *= fac; o1[i2] *= fac; }
    }

    // ---- raw-rate exp2 + tree sum ----
#pragma unroll
    for (int c = 0; c < 2; ++c)
#pragma unroll
      for (int i2 = 0; i2 < 16; ++i2) sc[c][i2] = fexp2(sc[c][i2] - m);
    float ts[16];
#pragma unroll
    for (int i2 = 0; i2 < 16; ++i2) ts[i2] = sc[0][i2] + sc[1][i2];
#pragma unroll
    for (int d = 8; d; d >>= 1)
#pragma unroll
      for (int i2 = 0; i2 < d; ++i2) ts[i2] += ts[i2 + d];
    lsum += ts[0] + __shfl_xor(ts[0], 32, 64);

    // ---- PV: 4 s-steps of 16 kv; V already in regs ----
#pragma unroll
    for (int s = 0; s < 4; ++s) {
      const f32x16& sf = sc[s >> 1];
      const int rb = (s & 1) * 8;
      unsigned d0 = pkbf(sf[rb + 0], sf[rb + 1]);
      unsigned d1 = pkbf(sf[rb + 2], sf[rb + 3]);
      unsigned d2 = pkbf(sf[rb + 4], sf[rb + 5]);
      unsigned d3 = pkbf(sf[rb + 6], sf[rb + 7]);
      pl32swap(d0, d2);
      pl32swap(d1, d3);
      union { unsigned u[4]; bf16x8 v; } pu;
      pu.u[0] = d0; pu.u[1] = d1; pu.u[2] = d2; pu.u[3] = d3;
      __builtin_amdgcn_s_setprio(1);
      o0 = __builtin_amdgcn_mfma_f32_32x32x16_bf16(vv[2 * s],     pu.v, o0, 0, 0, 0);
      o1 = __builtin_amdgcn_mfma_f32_32x32x16_bf16(vv[2 * s + 1], pu.v, o1, 0, 0, 0);
      __builtin_amdgcn_s_setprio(0);
    }

    __syncthreads();   // K staging had the whole iteration in flight
    pb ^= 1;
  }

  // ---- kv-group merge via LDS (reuse lK) ----
  float* mb = (float*)&lK[0][0];
  int base = (qc * 64 + lane) * 34;
  if (g) {
#pragma unroll
    for (int i2 = 0; i2 < 16; ++i2) { mb[base + i2] = o0[i2]; mb[base + 16 + i2] = o1[i2]; }
    mb[base + 32] = m; mb[base + 33] = lsum;
  }
  __syncthreads();
  if (!g) {
    float m1 = mb[base + 32], l1 = mb[base + 33];
    float mn = fmaxf(m, m1);
    float f0 = fexp2(m - mn), f1 = fexp2(m1 - mn);
    float linv = 1.0f / (lsum * f0 + l1 * f1);
    float a0 = f0 * linv, a1 = f1 * linv;
    int b = bh >> 4, h = bh & 15;
    unsigned short* ob = O + ((size_t)(b * 2048 + q)) * 1024 + h * 64;
#pragma unroll
    for (int gg = 0; gg < 4; ++gg) {
      uint2 w;
      w.x = pkbf(o0[4 * gg + 0] * a0 + mb[base + 4 * gg + 0] * a1,
                 o0[4 * gg + 1] * a0 + mb[base + 4 * gg + 1] * a1);
      w.y = pkbf(o0[4 * gg + 2] * a0 + mb[base + 4 * gg + 2] * a1,
                 o0[4 * gg + 3] * a0 + mb[base + 4 * gg + 3] * a1);
      *(uint2*)(ob + 8 * gg + 4 * hi) = w;
      w.x = pkbf(o1[4 * gg + 0] * a0 + mb[base + 16 + 4 * gg + 0] * a1,
                 o1[4 * gg + 1] * a0 + mb[base + 16 + 4 * gg + 1] * a1);
      w.y = pkbf(o1[4 * gg + 2] * a0 + mb[base + 16 + 4 * gg + 2] * a1,
                 o1[4 * gg + 3] * a0 + mb[base + 16 + 4 * gg + 3] * a1);
      *(uint2*)(ob + 32 + 8 * gg + 4 * hi) = w;
    }
  }
}

extern "C" void kernel_launch(void* const* d_in, const int* in_sizes, int n_in,
                              void* d_out, int out_size, void* d_ws, size_t ws_size,
                              hipStream_t stream)
{
  (void)in_sizes; (void)n_in; (void)out_size; (void)ws_size;
  const float* x      = (const float*)d_in[0];
  const float* w_qkv  = (const float*)d_in[1];
  const float* b_qkv  = (const float*)d_in[2];
  const float* w_proj = (const float*)d_in[3];
  const float* b_proj = (const float*)d_in[4];
  const float* q_g    = (const float*)d_in[5];
  const float* q_b    = (const float*)d_in[6];
  const float* k_g    = (const float*)d_in[7];
  const float* k_b    = (const float*)d_in[8];
  float* out = (float*)d_out;

  char* p = (char*)d_ws;
  unsigned short* x_bf  = (unsigned short*)p;  p += (size_t)4096 * 1024 * 2;
  unsigned short* wq_bf = (unsigned short*)p;  p += (size_t)3072 * 1024 * 2;
  unsigned short* wp_bf = (unsigned short*)p;  p += (size_t)1024 * 1024 * 2;
  unsigned short* qh    = (unsigned short*)p;  p += (size_t)32 * 2048 * 64 * 2;
  unsigned short* kh    = (unsigned short*)p;  p += (size_t)32 * 2048 * 64 * 2;
  unsigned short* vfr   = (unsigned short*)p;  p += (size_t)32 * 131072 * 2;
  unsigned short* ao    = (unsigned short*)p;  p += (size_t)4096 * 1024 * 2;

  k_cvt3<<<8192, 256, 0, stream>>>(x, w_qkv, w_proj, x_bf);   // outs contiguous

  k_gemm_qkv<<<dim3(24, 32), 256, 0, stream>>>(x_bf, wq_bf, b_qkv,
                                               q_g, q_b, k_g, k_b, qh, kh, vfr);
  k_attn<<<1024, 256, 0, stream>>>(qh, kh, vfr, ao);
  k_gemm<64, 128, 1, 4><<<dim3(8, 64), 256, 0, stream>>>(ao, wp_bf, b_proj, out, 4096, 1024, 1024);
}